// Round 7
// baseline (347.608 us; speedup 1.0000x reference)
//
#include <hip/hip_runtime.h>
#include <hip/hip_bf16.h>

typedef unsigned int uint;

// B=2, N=512, D=256, H=8, HD=32, DFF=1024
constexpr float EPS_ = 1e-5f;

#define DEV __device__ __forceinline__

DEV float gelu_(float x){ return 0.5f*x*(1.f + erff(x*0.70710678118654752f)); }

// ---------------- setup: GW[d][h]=g_d*We[d,h], A[h]=sum GW, C[h]=sum b_d*We+be ----------------
__global__ __launch_bounds__(256) void k_setup(
    const float* __restrict__ g, const float* __restrict__ b,
    const float* __restrict__ We, const float* __restrict__ be,
    float* __restrict__ GW, float* __restrict__ A, float* __restrict__ C)
{
    const int d = threadIdx.x;
    __shared__ float redA[256*8];
    __shared__ float redC[256*8];
    float gd = g[d], bd = b[d];
    #pragma unroll
    for (int h = 0; h < 8; ++h) {
        float w = We[d*8+h];
        float gw = gd*w;
        GW[d*8+h] = gw;
        redA[d*8+h] = gw;
        redC[d*8+h] = bd*w;
    }
    __syncthreads();
    for (int s = 128; s >= 1; s >>= 1) {
        if (d < s) {
            #pragma unroll
            for (int h = 0; h < 8; ++h) {
                redA[d*8+h] += redA[(d+s)*8+h];
                redC[d*8+h] += redC[(d+s)*8+h];
            }
        }
        __syncthreads();
    }
    if (d < 8) {
        A[d] = redA[d];
        C[d] = redC[d] + be[d];
    }
}

// ---------------- node LN + QKV projection: 4 rows/block, grid 256 ----------------
// Wave w owns LN of row r0+w (shfl-only). LN values staged transposed: sxT[d] = float4(rows).
// d-loop: 1 ds_read_b128 broadcast + 3 coalesced weight loads + 12 FMA.
__global__ __launch_bounds__(256) void k_qkv(
    const float* __restrict__ x,
    const float* __restrict__ g, const float* __restrict__ bta,
    const float* __restrict__ Wq, const float* __restrict__ bq,
    const float* __restrict__ Wk, const float* __restrict__ bk,
    const float* __restrict__ Wv, const float* __restrict__ bv,
    float* __restrict__ q, float* __restrict__ k, float* __restrict__ v)
{
    const int t = threadIdx.x;
    const int wid = t >> 6, l = t & 63;
    const int r0 = blockIdx.x << 2;
    __shared__ float sxT[256*4];          // [d][row]
    {
        const int row = r0 + wid;
        const float4 xv4 = ((const float4*)x)[row*64 + l];
        float s  = xv4.x + xv4.y + xv4.z + xv4.w;
        float q2 = xv4.x*xv4.x + xv4.y*xv4.y + xv4.z*xv4.z + xv4.w*xv4.w;
        #pragma unroll
        for (int o = 32; o >= 1; o >>= 1) { s += __shfl_xor(s, o); q2 += __shfl_xor(q2, o); }
        const float m = s * (1.f/256.f);
        const float rinv = rsqrtf(q2*(1.f/256.f) - m*m + EPS_);
        const float4 g4 = ((const float4*)g)[l];
        const float4 b4 = ((const float4*)bta)[l];
        sxT[(4*l+0)*4 + wid] = (xv4.x - m)*rinv*g4.x + b4.x;
        sxT[(4*l+1)*4 + wid] = (xv4.y - m)*rinv*g4.y + b4.y;
        sxT[(4*l+2)*4 + wid] = (xv4.z - m)*rinv*g4.z + b4.z;
        sxT[(4*l+3)*4 + wid] = (xv4.w - m)*rinv*g4.w + b4.w;
    }
    __syncthreads();
    const float bqv = bq[t], bkv = bk[t], bvv = bv[t];
    float4 AQ = make_float4(bqv,bqv,bqv,bqv);
    float4 AK = make_float4(bkv,bkv,bkv,bkv);
    float4 AV = make_float4(bvv,bvv,bvv,bvv);
    for (int d = 0; d < 256; ++d) {
        const float4 s4 = *((const float4*)&sxT[d*4]);
        const float wq = Wq[d*256 + t], wk = Wk[d*256 + t], wv = Wv[d*256 + t];
        AQ.x = fmaf(s4.x, wq, AQ.x); AQ.y = fmaf(s4.y, wq, AQ.y);
        AQ.z = fmaf(s4.z, wq, AQ.z); AQ.w = fmaf(s4.w, wq, AQ.w);
        AK.x = fmaf(s4.x, wk, AK.x); AK.y = fmaf(s4.y, wk, AK.y);
        AK.z = fmaf(s4.z, wk, AK.z); AK.w = fmaf(s4.w, wk, AK.w);
        AV.x = fmaf(s4.x, wv, AV.x); AV.y = fmaf(s4.y, wv, AV.y);
        AV.z = fmaf(s4.z, wv, AV.z); AV.w = fmaf(s4.w, wv, AV.w);
    }
    q[(r0+0)*256 + t] = AQ.x; q[(r0+1)*256 + t] = AQ.y;
    q[(r0+2)*256 + t] = AQ.z; q[(r0+3)*256 + t] = AQ.w;
    k[(r0+0)*256 + t] = AK.x; k[(r0+1)*256 + t] = AK.y;
    k[(r0+2)*256 + t] = AK.z; k[(r0+3)*256 + t] = AK.w;
    v[(r0+0)*256 + t] = AV.x; v[(r0+1)*256 + t] = AV.y;
    v[(r0+2)*256 + t] = AV.z; v[(r0+3)*256 + t] = AV.w;
}

// ---------------- fused: edge LN->bias->mask + attention for one (b,i) ----------------
__global__ __launch_bounds__(256) void k_eattn(
    const float4* __restrict__ ep,        // edge as float4: 64 per 256-elem row
    const int*   __restrict__ msk,        // (B,N,N)
    const float* __restrict__ GW, const float* __restrict__ Avec, const float* __restrict__ Cvec,
    const float* __restrict__ qg, const float* __restrict__ kg, const float* __restrict__ vg,
    float* __restrict__ ao)               // (B,N,D) f32
{
    __shared__ float slds[256*33];        // 33792 B staging
    __shared__ float sgw[2048];           // 8 KB GW table
    __shared__ float sac[16];
    __shared__ float sb[8*512];           // [h][j] bias + mask, 16 KB
    __shared__ float sp[8*512];           // [h][j] probs, 16 KB
    __shared__ float sqv[256];            // q row, pre-scaled
    __shared__ float sden[8];
    const int t = threadIdx.x;
    const int bi = blockIdx.x;            // b*512 + i
    const int b = bi >> 9;
    #pragma unroll
    for (int kk = 0; kk < 8; ++kk) sgw[kk*256 + t] = GW[kk*256 + t];
    if (t < 8) { sac[t] = Avec[t]; sac[8 + t] = Cvec[t]; }
    sqv[t] = qg[(size_t)bi*256 + t] * 0.17677669529663687f;   // 1/sqrt(32)
    __syncthreads();

    // ---- edge bias for all 512 keys, two halves of 256 rows ----
    for (int half = 0; half < 2; ++half) {
        const long long rowBase = ((long long)bi << 9) + (half << 8);  // (b,i,j0)
        float sum = 0.f, ssq = 0.f;
        float S[8] = {0.f,0.f,0.f,0.f,0.f,0.f,0.f,0.f};
        for (int c = 0; c < 8; ++c) {     // 8 chunks of 32 floats per row
            #pragma unroll
            for (int kk = 0; kk < 8; ++kk) {
                int l2 = (kk << 8) + t;
                int r = l2 >> 3, u = l2 & 7;
                float4 val = ep[(rowBase + r)*64 + (c << 3) + u];
                float* dst = &slds[r*33 + (u << 2)];
                dst[0] = val.x; dst[1] = val.y; dst[2] = val.z; dst[3] = val.w;
            }
            __syncthreads();
            const float* srow = &slds[t*33];
            const int dbase = c << 5;
            #pragma unroll 4
            for (int j = 0; j < 32; ++j) {
                float e = srow[j];
                const float4* g4p = (const float4*)&sgw[(dbase + j) << 3]; // uniform -> broadcast
                const float4 ga = g4p[0], gb = g4p[1];
                sum += e;
                ssq = fmaf(e, e, ssq);
                S[0] = fmaf(e, ga.x, S[0]); S[1] = fmaf(e, ga.y, S[1]);
                S[2] = fmaf(e, ga.z, S[2]); S[3] = fmaf(e, ga.w, S[3]);
                S[4] = fmaf(e, gb.x, S[4]); S[5] = fmaf(e, gb.y, S[5]);
                S[6] = fmaf(e, gb.z, S[6]); S[7] = fmaf(e, gb.w, S[7]);
            }
            __syncthreads();
        }
        const float m = sum * (1.f/256.f);
        const float rinv = rsqrtf(ssq*(1.f/256.f) - m*m + EPS_);
        const float mb = (msk[rowBase + t] == 0) ? -1e30f : 0.f;
        const int jrow = (half << 8) + t;
        #pragma unroll
        for (int h = 0; h < 8; ++h)
            sb[h*512 + jrow] = rinv * (S[h] - m * sac[h]) + sac[8 + h] + mb;
    }
    __syncthreads();                      // sb complete

    // ---- scores + softmax: head h = t>>5, lane l = t&31 owns keys j = l + 32m ----
    const int h = t >> 5, l = t & 31;
    const float* kb = kg + ((size_t)b << 9)*256 + h*32;
    const float4* qr = (const float4*)(sqv + h*32);
    float sc[16];
    float pmax = -3.0e38f;
    #pragma unroll
    for (int mi = 0; mi < 16; ++mi) {
        const int j = l + (mi << 5);
        const float4* kr = (const float4*)(kb + (size_t)j*256);
        float a = 0.f;
        #pragma unroll
        for (int w = 0; w < 8; ++w) {
            float4 kv = kr[w], qv = qr[w];
            a += kv.x*qv.x + kv.y*qv.y + kv.z*qv.z + kv.w*qv.w;
        }
        float s0 = a + sb[h*512 + j];
        sc[mi] = s0;
        pmax = fmaxf(pmax, s0);
    }
    #pragma unroll
    for (int o = 16; o >= 1; o >>= 1) pmax = fmaxf(pmax, __shfl_xor(pmax, o));
    float psum = 0.f;
    #pragma unroll
    for (int mi = 0; mi < 16; ++mi) {
        float p = __expf(sc[mi] - pmax);
        sp[h*512 + l + (mi << 5)] = p;
        psum += p;
    }
    #pragma unroll
    for (int o = 16; o >= 1; o >>= 1) psum += __shfl_xor(psum, o);
    if (l == 0) sden[h] = psum;
    __syncthreads();

    // ---- PV: thread t owns output channel t (= h*32+l); coalesced v reads ----
    const float* vb = vg + ((size_t)b << 9)*256 + t;
    const float* spr = &sp[h*512];
    float a0 = 0.f, a1 = 0.f, a2 = 0.f, a3 = 0.f;
    for (int j = 0; j < 512; j += 4) {
        a0 = fmaf(spr[j],   vb[(size_t)(j)*256],   a0);
        a1 = fmaf(spr[j+1], vb[(size_t)(j+1)*256], a1);
        a2 = fmaf(spr[j+2], vb[(size_t)(j+2)*256], a2);
        a3 = fmaf(spr[j+3], vb[(size_t)(j+3)*256], a3);
    }
    ao[(size_t)bi*256 + t] = (a0+a1+a2+a3) / sden[h];
}

// ---------------- output projection + residual: 4 rows/block, grid 256 ----------------
__global__ __launch_bounds__(256) void k_proj(
    const float* __restrict__ at, const float* __restrict__ Wo,
    const float* __restrict__ bo, const float* __restrict__ x,
    float* __restrict__ x1)
{
    const int t = threadIdx.x;
    const int wid = t >> 6, l = t & 63;
    const int r0 = blockIdx.x << 2;
    __shared__ float saT[256*4];          // [d][row]
    {
        const float4 a4 = ((const float4*)at)[(r0 + wid)*64 + l];
        saT[(4*l+0)*4 + wid] = a4.x;
        saT[(4*l+1)*4 + wid] = a4.y;
        saT[(4*l+2)*4 + wid] = a4.z;
        saT[(4*l+3)*4 + wid] = a4.w;
    }
    __syncthreads();
    const float bov = bo[t];
    float4 A = make_float4(bov,bov,bov,bov);
    for (int d = 0; d < 256; ++d) {
        const float4 s4 = *((const float4*)&saT[d*4]);
        const float wo = Wo[d*256 + t];
        A.x = fmaf(s4.x, wo, A.x); A.y = fmaf(s4.y, wo, A.y);
        A.z = fmaf(s4.z, wo, A.z); A.w = fmaf(s4.w, wo, A.w);
    }
    x1[(r0+0)*256 + t] = A.x + x[(r0+0)*256 + t];
    x1[(r0+1)*256 + t] = A.y + x[(r0+1)*256 + t];
    x1[(r0+2)*256 + t] = A.z + x[(r0+2)*256 + t];
    x1[(r0+3)*256 + t] = A.w + x[(r0+3)*256 + t];
}

// ---------------- FFN: 4 rows/block, grid 256 ----------------
__global__ __launch_bounds__(256) void k_ff(
    const float* __restrict__ x1, const float* __restrict__ g,
    const float* __restrict__ bb,
    const float* __restrict__ W1, const float* __restrict__ b1,
    const float* __restrict__ W2, const float* __restrict__ b2,
    float* __restrict__ out)
{
    const int t = threadIdx.x;
    const int wid = t >> 6, l = t & 63;
    const int r0 = blockIdx.x << 2;
    __shared__ float shT[256*4];          // [d][row] LN values
    __shared__ float sfT[1024*4];         // [dff][row] gelu values
    {
        const int row = r0 + wid;
        const float4 xv4 = ((const float4*)x1)[row*64 + l];
        float s  = xv4.x + xv4.y + xv4.z + xv4.w;
        float q2 = xv4.x*xv4.x + xv4.y*xv4.y + xv4.z*xv4.z + xv4.w*xv4.w;
        #pragma unroll
        for (int o = 32; o >= 1; o >>= 1) { s += __shfl_xor(s, o); q2 += __shfl_xor(q2, o); }
        const float m = s * (1.f/256.f);
        const float rinv = rsqrtf(q2*(1.f/256.f) - m*m + EPS_);
        const float4 g4 = ((const float4*)g)[l];
        const float4 b4 = ((const float4*)bb)[l];
        shT[(4*l+0)*4 + wid] = (xv4.x - m)*rinv*g4.x + b4.x;
        shT[(4*l+1)*4 + wid] = (xv4.y - m)*rinv*g4.y + b4.y;
        shT[(4*l+2)*4 + wid] = (xv4.z - m)*rinv*g4.z + b4.z;
        shT[(4*l+3)*4 + wid] = (xv4.w - m)*rinv*g4.w + b4.w;
    }
    __syncthreads();
    const float bc0 = b1[t], bc1 = b1[t+256], bc2 = b1[t+512], bc3 = b1[t+768];
    float4 A0 = make_float4(bc0,bc0,bc0,bc0);
    float4 A1 = make_float4(bc1,bc1,bc1,bc1);
    float4 A2 = make_float4(bc2,bc2,bc2,bc2);
    float4 A3 = make_float4(bc3,bc3,bc3,bc3);
    for (int d = 0; d < 256; ++d) {
        const float4 s4 = *((const float4*)&shT[d*4]);
        const float* wr = W1 + d*1024 + t;
        const float w0 = wr[0], w1 = wr[256], w2 = wr[512], w3 = wr[768];
        A0.x = fmaf(s4.x, w0, A0.x); A0.y = fmaf(s4.y, w0, A0.y);
        A0.z = fmaf(s4.z, w0, A0.z); A0.w = fmaf(s4.w, w0, A0.w);
        A1.x = fmaf(s4.x, w1, A1.x); A1.y = fmaf(s4.y, w1, A1.y);
        A1.z = fmaf(s4.z, w1, A1.z); A1.w = fmaf(s4.w, w1, A1.w);
        A2.x = fmaf(s4.x, w2, A2.x); A2.y = fmaf(s4.y, w2, A2.y);
        A2.z = fmaf(s4.z, w2, A2.z); A2.w = fmaf(s4.w, w2, A2.w);
        A3.x = fmaf(s4.x, w3, A3.x); A3.y = fmaf(s4.y, w3, A3.y);
        A3.z = fmaf(s4.z, w3, A3.z); A3.w = fmaf(s4.w, w3, A3.w);
    }
    *((float4*)&sfT[(t      )*4]) = make_float4(gelu_(A0.x), gelu_(A0.y), gelu_(A0.z), gelu_(A0.w));
    *((float4*)&sfT[(t +  256)*4]) = make_float4(gelu_(A1.x), gelu_(A1.y), gelu_(A1.z), gelu_(A1.w));
    *((float4*)&sfT[(t +  512)*4]) = make_float4(gelu_(A2.x), gelu_(A2.y), gelu_(A2.z), gelu_(A2.w));
    *((float4*)&sfT[(t +  768)*4]) = make_float4(gelu_(A3.x), gelu_(A3.y), gelu_(A3.z), gelu_(A3.w));
    __syncthreads();
    const float b2v = b2[t];
    float4 AO = make_float4(b2v,b2v,b2v,b2v);
    for (int kk = 0; kk < 1024; ++kk) {
        const float4 s4 = *((const float4*)&sfT[kk*4]);
        const float w = W2[kk*256 + t];
        AO.x = fmaf(s4.x, w, AO.x); AO.y = fmaf(s4.y, w, AO.y);
        AO.z = fmaf(s4.z, w, AO.z); AO.w = fmaf(s4.w, w, AO.w);
    }
    out[(r0+0)*256 + t] = AO.x + x1[(r0+0)*256 + t];
    out[(r0+1)*256 + t] = AO.y + x1[(r0+1)*256 + t];
    out[(r0+2)*256 + t] = AO.z + x1[(r0+2)*256 + t];
    out[(r0+3)*256 + t] = AO.w + x1[(r0+3)*256 + t];
}

extern "C" void kernel_launch(void* const* d_in, const int* in_sizes, int n_in,
                              void* d_out, int out_size, void* d_ws, size_t ws_size,
                              hipStream_t stream) {
    const float* x   = (const float*)d_in[0];
    const float* ef  = (const float*)d_in[1];
    const int*   am  = (const int*)d_in[2];
    const float* ng  = (const float*)d_in[3];
    const float* nb  = (const float*)d_in[4];
    const float* eg  = (const float*)d_in[5];
    const float* ebb = (const float*)d_in[6];
    const float* Wq  = (const float*)d_in[7];
    const float* bq  = (const float*)d_in[8];
    const float* Wk  = (const float*)d_in[9];
    const float* bk  = (const float*)d_in[10];
    const float* Wv  = (const float*)d_in[11];
    const float* bv  = (const float*)d_in[12];
    const float* Wo  = (const float*)d_in[13];
    const float* bo  = (const float*)d_in[14];
    const float* We  = (const float*)d_in[15];
    const float* be  = (const float*)d_in[16];
    const float* fg  = (const float*)d_in[17];
    const float* fb  = (const float*)d_in[18];
    const float* W1  = (const float*)d_in[19];
    const float* b1  = (const float*)d_in[20];
    const float* W2  = (const float*)d_in[21];
    const float* b2  = (const float*)d_in[22];

    float* ws  = (float*)d_ws;
    float* GW  = ws;                      // 2048 f
    float* Av  = ws + 2048;               // 8 f
    float* Cv  = ws + 2064;               // 8 f
    float* q   = ws + 4096;               // 262144 f (B,N,D)
    float* k   = q  + 262144;
    float* v   = k  + 262144;
    float* ao  = v  + 262144;             // 262144 f (B,N,D)
    float* x1  = ao + 262144;             // 262144 f  -> total ~5.3 MB

    hipLaunchKernelGGL(k_setup, dim3(1), dim3(256), 0, stream, eg, ebb, We, be, GW, Av, Cv);
    hipLaunchKernelGGL(k_qkv, dim3(256), dim3(256), 0, stream,
                       x, ng, nb, Wq, bq, Wk, bk, Wv, bv, q, k, v);
    hipLaunchKernelGGL(k_eattn, dim3(1024), dim3(256), 0, stream,
                       (const float4*)ef, am, GW, Av, Cv, q, k, v, ao);
    hipLaunchKernelGGL(k_proj, dim3(256), dim3(256), 0, stream, ao, Wo, bo, x, x1);
    hipLaunchKernelGGL(k_ff, dim3(256), dim3(256), 0, stream,
                       x1, fg, fb, W1, b1, W2, b2, (float*)d_out);
}

// Round 8
// 330.691 us; speedup vs baseline: 1.0512x; 1.0512x over previous
//
#include <hip/hip_runtime.h>
#include <hip/hip_bf16.h>

typedef unsigned int uint;

// B=2, N=512, D=256, H=8, HD=32, DFF=1024
constexpr float EPS_ = 1e-5f;

#define DEV __device__ __forceinline__

DEV float gelu_(float x){ return 0.5f*x*(1.f + erff(x*0.70710678118654752f)); }

// ---------------- setup: GW[d][h]=g_d*We[d,h], A[h]=sum GW, C[h]=sum b_d*We+be ----------------
__global__ __launch_bounds__(256) void k_setup(
    const float* __restrict__ g, const float* __restrict__ b,
    const float* __restrict__ We, const float* __restrict__ be,
    float* __restrict__ GW, float* __restrict__ A, float* __restrict__ C)
{
    const int d = threadIdx.x;
    __shared__ float redA[256*8];
    __shared__ float redC[256*8];
    float gd = g[d], bd = b[d];
    #pragma unroll
    for (int h = 0; h < 8; ++h) {
        float w = We[d*8+h];
        float gw = gd*w;
        GW[d*8+h] = gw;
        redA[d*8+h] = gw;
        redC[d*8+h] = bd*w;
    }
    __syncthreads();
    for (int s = 128; s >= 1; s >>= 1) {
        if (d < s) {
            #pragma unroll
            for (int h = 0; h < 8; ++h) {
                redA[d*8+h] += redA[(d+s)*8+h];
                redC[d*8+h] += redC[(d+s)*8+h];
            }
        }
        __syncthreads();
    }
    if (d < 8) {
        A[d] = redA[d];
        C[d] = redC[d] + be[d];
    }
}

// ---------------- node LN + QKV: 2 rows/block, grid 512 (2 blocks/CU) ----------------
__global__ __launch_bounds__(256) void k_qkv(
    const float* __restrict__ x,
    const float* __restrict__ g, const float* __restrict__ bta,
    const float* __restrict__ Wq, const float* __restrict__ bq,
    const float* __restrict__ Wk, const float* __restrict__ bk,
    const float* __restrict__ Wv, const float* __restrict__ bv,
    float* __restrict__ q, float* __restrict__ k, float* __restrict__ v)
{
    const int t = threadIdx.x;
    const int wid = t >> 6, l = t & 63;
    const int r0 = blockIdx.x << 1;
    __shared__ float sxT[256*2];          // [d][row]
    if (wid < 2) {
        const int row = r0 + wid;
        const float4 xv4 = ((const float4*)x)[row*64 + l];
        float s  = xv4.x + xv4.y + xv4.z + xv4.w;
        float q2 = xv4.x*xv4.x + xv4.y*xv4.y + xv4.z*xv4.z + xv4.w*xv4.w;
        #pragma unroll
        for (int o = 32; o >= 1; o >>= 1) { s += __shfl_xor(s, o); q2 += __shfl_xor(q2, o); }
        const float m = s * (1.f/256.f);
        const float rinv = rsqrtf(q2*(1.f/256.f) - m*m + EPS_);
        const float4 g4 = ((const float4*)g)[l];
        const float4 b4 = ((const float4*)bta)[l];
        sxT[(4*l+0)*2 + wid] = (xv4.x - m)*rinv*g4.x + b4.x;
        sxT[(4*l+1)*2 + wid] = (xv4.y - m)*rinv*g4.y + b4.y;
        sxT[(4*l+2)*2 + wid] = (xv4.z - m)*rinv*g4.z + b4.z;
        sxT[(4*l+3)*2 + wid] = (xv4.w - m)*rinv*g4.w + b4.w;
    }
    __syncthreads();
    float aq0 = bq[t], ak0 = bk[t], av0 = bv[t];
    float aq1 = aq0, ak1 = ak0, av1 = av0;
    for (int d = 0; d < 256; d += 2) {
        const float4 s4 = *((const float4*)&sxT[d*2]);   // (d,r0)(d,r1)(d+1,r0)(d+1,r1)
        const float wqa = Wq[d*256 + t], wqb = Wq[(d+1)*256 + t];
        const float wka = Wk[d*256 + t], wkb = Wk[(d+1)*256 + t];
        const float wva = Wv[d*256 + t], wvb = Wv[(d+1)*256 + t];
        aq0 = fmaf(s4.x, wqa, aq0); aq0 = fmaf(s4.z, wqb, aq0);
        aq1 = fmaf(s4.y, wqa, aq1); aq1 = fmaf(s4.w, wqb, aq1);
        ak0 = fmaf(s4.x, wka, ak0); ak0 = fmaf(s4.z, wkb, ak0);
        ak1 = fmaf(s4.y, wka, ak1); ak1 = fmaf(s4.w, wkb, ak1);
        av0 = fmaf(s4.x, wva, av0); av0 = fmaf(s4.z, wvb, av0);
        av1 = fmaf(s4.y, wva, av1); av1 = fmaf(s4.w, wvb, av1);
    }
    q[(r0+0)*256 + t] = aq0; q[(r0+1)*256 + t] = aq1;
    k[(r0+0)*256 + t] = ak0; k[(r0+1)*256 + t] = ak1;
    v[(r0+0)*256 + t] = av0; v[(r0+1)*256 + t] = av1;
}

// ---------------- fused: edge LN->bias->mask + attention for one (b,i) ----------------
// GW/Av/Cv read via UNIFORM global loads -> s_load/SGPR broadcast (no LDS).
__global__ __launch_bounds__(256) void k_eattn(
    const float4* __restrict__ ep,        // edge as float4: 64 per 256-elem row
    const int*   __restrict__ msk,        // (B,N,N)
    const float* __restrict__ GWg, const float* __restrict__ Avec, const float* __restrict__ Cvec,
    const float* __restrict__ qg, const float* __restrict__ kg, const float* __restrict__ vg,
    float* __restrict__ ao)               // (B,N,D) f32
{
    __shared__ float slds[256*33];        // 33792 B staging
    __shared__ float sb[8*512];           // [h][j] bias + mask, 16 KB
    __shared__ float sp[8*512];           // [h][j] probs, 16 KB
    __shared__ float sqv[256];            // q row, pre-scaled
    __shared__ float sden[8];
    const int t = threadIdx.x;
    const int bi = blockIdx.x;            // b*512 + i
    const int b = bi >> 9;
    sqv[t] = qg[(size_t)bi*256 + t] * 0.17677669529663687f;   // 1/sqrt(32)
    __syncthreads();

    // ---- edge bias for all 512 keys, two halves of 256 rows ----
    for (int half = 0; half < 2; ++half) {
        const long long rowBase = ((long long)bi << 9) + (half << 8);  // (b,i,j0)
        float sum = 0.f, ssq = 0.f;
        float S[8] = {0.f,0.f,0.f,0.f,0.f,0.f,0.f,0.f};
        for (int c = 0; c < 8; ++c) {     // 8 chunks of 32 floats per row
            #pragma unroll
            for (int kk = 0; kk < 8; ++kk) {
                int l2 = (kk << 8) + t;
                int r = l2 >> 3, u = l2 & 7;
                float4 val = ep[(rowBase + r)*64 + (c << 3) + u];
                *((float4*)&slds[r*33 + (u << 2)]) = val;
            }
            __syncthreads();
            const float* srow = &slds[t*33];
            const int dbase = c << 5;
            #pragma unroll
            for (int j4 = 0; j4 < 8; ++j4) {
                const float4 e4 = *((const float4*)&srow[j4 << 2]);
                const int d0 = dbase + (j4 << 2);
                #pragma unroll
                for (int u = 0; u < 4; ++u) {
                    const float e = (u==0) ? e4.x : (u==1) ? e4.y : (u==2) ? e4.z : e4.w;
                    const float* gw = &GWg[(size_t)(d0 + u) << 3];  // uniform -> SGPR
                    sum += e;
                    ssq = fmaf(e, e, ssq);
                    S[0] = fmaf(e, gw[0], S[0]); S[1] = fmaf(e, gw[1], S[1]);
                    S[2] = fmaf(e, gw[2], S[2]); S[3] = fmaf(e, gw[3], S[3]);
                    S[4] = fmaf(e, gw[4], S[4]); S[5] = fmaf(e, gw[5], S[5]);
                    S[6] = fmaf(e, gw[6], S[6]); S[7] = fmaf(e, gw[7], S[7]);
                }
            }
            __syncthreads();
        }
        const float m = sum * (1.f/256.f);
        const float rinv = rsqrtf(ssq*(1.f/256.f) - m*m + EPS_);
        const float mb = (msk[rowBase + t] == 0) ? -1e30f : 0.f;
        const int jrow = (half << 8) + t;
        #pragma unroll
        for (int h = 0; h < 8; ++h)
            sb[h*512 + jrow] = rinv * (S[h] - m * Avec[h]) + Cvec[h] + mb;  // Avec/Cvec uniform
    }
    __syncthreads();                      // sb complete

    // ---- scores + softmax: head h = t>>5, lane l = t&31 owns keys j = l + 32m ----
    const int h = t >> 5, l = t & 31;
    const float* kb = kg + ((size_t)b << 9)*256 + h*32;
    float4 qv[8];
    {
        const float4* qr = (const float4*)(sqv + h*32);
        #pragma unroll
        for (int w = 0; w < 8; ++w) qv[w] = qr[w];    // hoist q into regs
    }
    float sc[16];
    float pmax = -3.0e38f;
    #pragma unroll
    for (int mi = 0; mi < 16; ++mi) {
        const int j = l + (mi << 5);
        const float4* kr = (const float4*)(kb + (size_t)j*256);
        float a = 0.f;
        #pragma unroll
        for (int w = 0; w < 8; ++w) {
            const float4 kv = kr[w];
            a += kv.x*qv[w].x + kv.y*qv[w].y + kv.z*qv[w].z + kv.w*qv[w].w;
        }
        float s0 = a + sb[h*512 + j];
        sc[mi] = s0;
        pmax = fmaxf(pmax, s0);
    }
    #pragma unroll
    for (int o = 16; o >= 1; o >>= 1) pmax = fmaxf(pmax, __shfl_xor(pmax, o));
    float psum = 0.f;
    #pragma unroll
    for (int mi = 0; mi < 16; ++mi) {
        float p = __expf(sc[mi] - pmax);
        sp[h*512 + l + (mi << 5)] = p;
        psum += p;
    }
    #pragma unroll
    for (int o = 16; o >= 1; o >>= 1) psum += __shfl_xor(psum, o);
    if (l == 0) sden[h] = psum;
    __syncthreads();

    // ---- PV: thread t owns output channel t; float4 prob reads (broadcast) ----
    const float* vb = vg + ((size_t)b << 9)*256 + t;
    const float4* spr4 = (const float4*)&sp[h*512];
    float a0 = 0.f, a1 = 0.f, a2 = 0.f, a3 = 0.f;
    for (int j4 = 0; j4 < 128; ++j4) {
        const float4 p4 = spr4[j4];
        const float* vj = vb + ((size_t)j4 << 2)*256;
        a0 = fmaf(p4.x, vj[0],   a0);
        a1 = fmaf(p4.y, vj[256], a1);
        a2 = fmaf(p4.z, vj[512], a2);
        a3 = fmaf(p4.w, vj[768], a3);
    }
    ao[(size_t)bi*256 + t] = (a0+a1+a2+a3) / sden[h];
}

// ---------------- output projection + residual: 2 rows/block, grid 512 ----------------
__global__ __launch_bounds__(256) void k_proj(
    const float* __restrict__ at, const float* __restrict__ Wo,
    const float* __restrict__ bo, const float* __restrict__ x,
    float* __restrict__ x1)
{
    const int t = threadIdx.x;
    const int wid = t >> 6, l = t & 63;
    const int r0 = blockIdx.x << 1;
    __shared__ float saT[256*2];          // [d][row]
    if (wid < 2) {
        const float4 a4 = ((const float4*)at)[(r0 + wid)*64 + l];
        saT[(4*l+0)*2 + wid] = a4.x;
        saT[(4*l+1)*2 + wid] = a4.y;
        saT[(4*l+2)*2 + wid] = a4.z;
        saT[(4*l+3)*2 + wid] = a4.w;
    }
    __syncthreads();
    float A0 = bo[t], A1 = A0;
    for (int d = 0; d < 256; d += 2) {
        const float4 s4 = *((const float4*)&saT[d*2]);
        const float wa = Wo[d*256 + t], wb = Wo[(d+1)*256 + t];
        A0 = fmaf(s4.x, wa, A0); A0 = fmaf(s4.z, wb, A0);
        A1 = fmaf(s4.y, wa, A1); A1 = fmaf(s4.w, wb, A1);
    }
    x1[(r0+0)*256 + t] = A0 + x[(r0+0)*256 + t];
    x1[(r0+1)*256 + t] = A1 + x[(r0+1)*256 + t];
}

// ---------------- FFN: 4 rows/block, grid 256; thread owns 4 consecutive DFF channels ----------------
__global__ __launch_bounds__(256) void k_ff(
    const float* __restrict__ x1, const float* __restrict__ g,
    const float* __restrict__ bb,
    const float* __restrict__ W1, const float* __restrict__ b1,
    const float* __restrict__ W2, const float* __restrict__ b2,
    float* __restrict__ out)
{
    const int t = threadIdx.x;
    const int wid = t >> 6, l = t & 63;
    const int r0 = blockIdx.x << 2;
    __shared__ float shT[256*4];          // [d][row] LN values
    __shared__ float sfT[1024*4];         // [dff][row] gelu values
    {
        const int row = r0 + wid;
        const float4 xv4 = ((const float4*)x1)[row*64 + l];
        float s  = xv4.x + xv4.y + xv4.z + xv4.w;
        float q2 = xv4.x*xv4.x + xv4.y*xv4.y + xv4.z*xv4.z + xv4.w*xv4.w;
        #pragma unroll
        for (int o = 32; o >= 1; o >>= 1) { s += __shfl_xor(s, o); q2 += __shfl_xor(q2, o); }
        const float m = s * (1.f/256.f);
        const float rinv = rsqrtf(q2*(1.f/256.f) - m*m + EPS_);
        const float4 g4 = ((const float4*)g)[l];
        const float4 b4 = ((const float4*)bb)[l];
        shT[(4*l+0)*4 + wid] = (xv4.x - m)*rinv*g4.x + b4.x;
        shT[(4*l+1)*4 + wid] = (xv4.y - m)*rinv*g4.y + b4.y;
        shT[(4*l+2)*4 + wid] = (xv4.z - m)*rinv*g4.z + b4.z;
        shT[(4*l+3)*4 + wid] = (xv4.w - m)*rinv*g4.w + b4.w;
    }
    __syncthreads();
    const float4 bc = ((const float4*)b1)[t];
    float4 Ac0 = make_float4(bc.x,bc.x,bc.x,bc.x);   // channel 4t+0, rows 0..3
    float4 Ac1 = make_float4(bc.y,bc.y,bc.y,bc.y);
    float4 Ac2 = make_float4(bc.z,bc.z,bc.z,bc.z);
    float4 Ac3 = make_float4(bc.w,bc.w,bc.w,bc.w);
    const float4* W14 = (const float4*)W1;
    for (int d = 0; d < 256; ++d) {
        const float4 s4 = *((const float4*)&shT[d*4]);   // rows 0..3
        const float4 w4 = W14[d*256 + t];                // channels 4t..4t+3
        Ac0.x = fmaf(s4.x, w4.x, Ac0.x); Ac0.y = fmaf(s4.y, w4.x, Ac0.y);
        Ac0.z = fmaf(s4.z, w4.x, Ac0.z); Ac0.w = fmaf(s4.w, w4.x, Ac0.w);
        Ac1.x = fmaf(s4.x, w4.y, Ac1.x); Ac1.y = fmaf(s4.y, w4.y, Ac1.y);
        Ac1.z = fmaf(s4.z, w4.y, Ac1.z); Ac1.w = fmaf(s4.w, w4.y, Ac1.w);
        Ac2.x = fmaf(s4.x, w4.z, Ac2.x); Ac2.y = fmaf(s4.y, w4.z, Ac2.y);
        Ac2.z = fmaf(s4.z, w4.z, Ac2.z); Ac2.w = fmaf(s4.w, w4.z, Ac2.w);
        Ac3.x = fmaf(s4.x, w4.w, Ac3.x); Ac3.y = fmaf(s4.y, w4.w, Ac3.y);
        Ac3.z = fmaf(s4.z, w4.w, Ac3.z); Ac3.w = fmaf(s4.w, w4.w, Ac3.w);
    }
    *((float4*)&sfT[(4*t+0)*4]) = make_float4(gelu_(Ac0.x), gelu_(Ac0.y), gelu_(Ac0.z), gelu_(Ac0.w));
    *((float4*)&sfT[(4*t+1)*4]) = make_float4(gelu_(Ac1.x), gelu_(Ac1.y), gelu_(Ac1.z), gelu_(Ac1.w));
    *((float4*)&sfT[(4*t+2)*4]) = make_float4(gelu_(Ac2.x), gelu_(Ac2.y), gelu_(Ac2.z), gelu_(Ac2.w));
    *((float4*)&sfT[(4*t+3)*4]) = make_float4(gelu_(Ac3.x), gelu_(Ac3.y), gelu_(Ac3.z), gelu_(Ac3.w));
    __syncthreads();
    const float b2v = b2[t];
    float4 AO = make_float4(b2v,b2v,b2v,b2v);
    for (int kk = 0; kk < 1024; ++kk) {
        const float4 s4 = *((const float4*)&sfT[kk*4]);
        const float w = W2[kk*256 + t];
        AO.x = fmaf(s4.x, w, AO.x); AO.y = fmaf(s4.y, w, AO.y);
        AO.z = fmaf(s4.z, w, AO.z); AO.w = fmaf(s4.w, w, AO.w);
    }
    out[(r0+0)*256 + t] = AO.x + x1[(r0+0)*256 + t];
    out[(r0+1)*256 + t] = AO.y + x1[(r0+1)*256 + t];
    out[(r0+2)*256 + t] = AO.z + x1[(r0+2)*256 + t];
    out[(r0+3)*256 + t] = AO.w + x1[(r0+3)*256 + t];
}

extern "C" void kernel_launch(void* const* d_in, const int* in_sizes, int n_in,
                              void* d_out, int out_size, void* d_ws, size_t ws_size,
                              hipStream_t stream) {
    const float* x   = (const float*)d_in[0];
    const float* ef  = (const float*)d_in[1];
    const int*   am  = (const int*)d_in[2];
    const float* ng  = (const float*)d_in[3];
    const float* nb  = (const float*)d_in[4];
    const float* eg  = (const float*)d_in[5];
    const float* ebb = (const float*)d_in[6];
    const float* Wq  = (const float*)d_in[7];
    const float* bq  = (const float*)d_in[8];
    const float* Wk  = (const float*)d_in[9];
    const float* bk  = (const float*)d_in[10];
    const float* Wv  = (const float*)d_in[11];
    const float* bv  = (const float*)d_in[12];
    const float* Wo  = (const float*)d_in[13];
    const float* bo  = (const float*)d_in[14];
    const float* We  = (const float*)d_in[15];
    const float* be  = (const float*)d_in[16];
    const float* fg  = (const float*)d_in[17];
    const float* fb  = (const float*)d_in[18];
    const float* W1  = (const float*)d_in[19];
    const float* b1  = (const float*)d_in[20];
    const float* W2  = (const float*)d_in[21];
    const float* b2  = (const float*)d_in[22];

    float* ws  = (float*)d_ws;
    float* GW  = ws;                      // 2048 f
    float* Av  = ws + 2048;               // 8 f
    float* Cv  = ws + 2064;               // 8 f
    float* q   = ws + 4096;               // 262144 f (B,N,D)
    float* k   = q  + 262144;
    float* v   = k  + 262144;
    float* ao  = v  + 262144;             // 262144 f (B,N,D)
    float* x1  = ao + 262144;             // 262144 f  -> total ~5.3 MB

    hipLaunchKernelGGL(k_setup, dim3(1), dim3(256), 0, stream, eg, ebb, We, be, GW, Av, Cv);
    hipLaunchKernelGGL(k_qkv, dim3(512), dim3(256), 0, stream,
                       x, ng, nb, Wq, bq, Wk, bk, Wv, bv, q, k, v);
    hipLaunchKernelGGL(k_eattn, dim3(1024), dim3(256), 0, stream,
                       (const float4*)ef, am, GW, Av, Cv, q, k, v, ao);
    hipLaunchKernelGGL(k_proj, dim3(512), dim3(256), 0, stream, ao, Wo, bo, x, x1);
    hipLaunchKernelGGL(k_ff, dim3(256), dim3(256), 0, stream,
                       x1, fg, fb, W1, b1, W2, b2, (float*)d_out);
}

// Round 9
// 292.967 us; speedup vs baseline: 1.1865x; 1.1288x over previous
//
#include <hip/hip_runtime.h>
#include <hip/hip_bf16.h>

typedef unsigned int uint;

// B=2, N=512, D=256, H=8, HD=32, DFF=1024
constexpr float EPS_ = 1e-5f;

#define DEV __device__ __forceinline__

DEV float gelu_(float x){ return 0.5f*x*(1.f + erff(x*0.70710678118654752f)); }

// ---------------- setup: GW[d][h]=g_d*We[d,h], A[h]=sum GW, C[h]=sum b_d*We+be ----------------
__global__ __launch_bounds__(256) void k_setup(
    const float* __restrict__ g, const float* __restrict__ b,
    const float* __restrict__ We, const float* __restrict__ be,
    float* __restrict__ GW, float* __restrict__ A, float* __restrict__ C)
{
    const int d = threadIdx.x;
    __shared__ float redA[256*8];
    __shared__ float redC[256*8];
    float gd = g[d], bd = b[d];
    #pragma unroll
    for (int h = 0; h < 8; ++h) {
        float w = We[d*8+h];
        float gw = gd*w;
        GW[d*8+h] = gw;
        redA[d*8+h] = gw;
        redC[d*8+h] = bd*w;
    }
    __syncthreads();
    for (int s = 128; s >= 1; s >>= 1) {
        if (d < s) {
            #pragma unroll
            for (int h = 0; h < 8; ++h) {
                redA[d*8+h] += redA[(d+s)*8+h];
                redC[d*8+h] += redC[(d+s)*8+h];
            }
        }
        __syncthreads();
    }
    if (d < 8) {
        A[d] = redA[d];
        C[d] = redC[d] + be[d];
    }
}

// ---------------- node LN + QKV: 2 rows/block, grid 512 ----------------
__global__ __launch_bounds__(256) void k_qkv(
    const float* __restrict__ x,
    const float* __restrict__ g, const float* __restrict__ bta,
    const float* __restrict__ Wq, const float* __restrict__ bq,
    const float* __restrict__ Wk, const float* __restrict__ bk,
    const float* __restrict__ Wv, const float* __restrict__ bv,
    float* __restrict__ q, float* __restrict__ k, float* __restrict__ v)
{
    const int t = threadIdx.x;
    const int wid = t >> 6, l = t & 63;
    const int r0 = blockIdx.x << 1;
    __shared__ float sxT[256*2];          // [d][row]
    if (wid < 2) {
        const int row = r0 + wid;
        const float4 xv4 = ((const float4*)x)[row*64 + l];
        float s  = xv4.x + xv4.y + xv4.z + xv4.w;
        float q2 = xv4.x*xv4.x + xv4.y*xv4.y + xv4.z*xv4.z + xv4.w*xv4.w;
        #pragma unroll
        for (int o = 32; o >= 1; o >>= 1) { s += __shfl_xor(s, o); q2 += __shfl_xor(q2, o); }
        const float m = s * (1.f/256.f);
        const float rinv = rsqrtf(q2*(1.f/256.f) - m*m + EPS_);
        const float4 g4 = ((const float4*)g)[l];
        const float4 b4 = ((const float4*)bta)[l];
        sxT[(4*l+0)*2 + wid] = (xv4.x - m)*rinv*g4.x + b4.x;
        sxT[(4*l+1)*2 + wid] = (xv4.y - m)*rinv*g4.y + b4.y;
        sxT[(4*l+2)*2 + wid] = (xv4.z - m)*rinv*g4.z + b4.z;
        sxT[(4*l+3)*2 + wid] = (xv4.w - m)*rinv*g4.w + b4.w;
    }
    __syncthreads();
    float aq0 = bq[t], ak0 = bk[t], av0 = bv[t];
    float aq1 = aq0, ak1 = ak0, av1 = av0;
    for (int d = 0; d < 256; d += 2) {
        const float4 s4 = *((const float4*)&sxT[d*2]);
        const float wqa = Wq[d*256 + t], wqb = Wq[(d+1)*256 + t];
        const float wka = Wk[d*256 + t], wkb = Wk[(d+1)*256 + t];
        const float wva = Wv[d*256 + t], wvb = Wv[(d+1)*256 + t];
        aq0 = fmaf(s4.x, wqa, aq0); aq0 = fmaf(s4.z, wqb, aq0);
        aq1 = fmaf(s4.y, wqa, aq1); aq1 = fmaf(s4.w, wqb, aq1);
        ak0 = fmaf(s4.x, wka, ak0); ak0 = fmaf(s4.z, wkb, ak0);
        ak1 = fmaf(s4.y, wka, ak1); ak1 = fmaf(s4.w, wkb, ak1);
        av0 = fmaf(s4.x, wva, av0); av0 = fmaf(s4.z, wvb, av0);
        av1 = fmaf(s4.y, wva, av1); av1 = fmaf(s4.w, wvb, av1);
    }
    q[(r0+0)*256 + t] = aq0; q[(r0+1)*256 + t] = aq1;
    k[(r0+0)*256 + t] = ak0; k[(r0+1)*256 + t] = ak1;
    v[(r0+0)*256 + t] = av0; v[(r0+1)*256 + t] = av1;
}

// ---------------- fused: edge LN bias + QK^T + softmax + PV for one (b,i) ----------------
// All K/edge bytes move coalesced (float4 global -> LDS, stride-20 padded rows).
// Thread t owns row t of each 256-row half for both edge-LN and K-dot phases.
__global__ __launch_bounds__(256) void k_eattn(
    const float4* __restrict__ ep,        // edge as float4: 64 per 256-elem row
    const int*   __restrict__ msk,        // (B,N,N)
    const float* __restrict__ GWg, const float* __restrict__ Avec, const float* __restrict__ Cvec,
    const float* __restrict__ qg, const float4* __restrict__ kg4, const float* __restrict__ vg,
    float* __restrict__ ao)               // (B,N,D) f32
{
    __shared__ float slds[256*20];        // 20480 B staging (stride 20: balanced banks)
    __shared__ float sb[8*512];           // [h][j] scores -> probs in place, 16 KB
    __shared__ float sqv[256];            // q row, pre-scaled
    __shared__ float sden[8];
    const int t = threadIdx.x;
    const int bi = blockIdx.x;            // b*512 + i
    const int b = bi >> 9;
    sqv[t] = qg[(size_t)bi*256 + t] * 0.17677669529663687f;   // 1/sqrt(32)
    __syncthreads();

    for (int half = 0; half < 2; ++half) {
        const long long rowBase = ((long long)bi << 9) + (half << 8);   // edge row (b,i,j0)
        const int krow0 = (b << 9) + (half << 8);                       // key row (b,j0)
        float sum = 0.f, ssq = 0.f;
        float S[8]  = {0.f,0.f,0.f,0.f,0.f,0.f,0.f,0.f};
        float qk[8] = {0.f,0.f,0.f,0.f,0.f,0.f,0.f,0.f};

        // ---- edge chunks: 16 chunks x 16 floats per row ----
        for (int c = 0; c < 16; ++c) {
            #pragma unroll
            for (int kk = 0; kk < 4; ++kk) {
                const int l2 = (kk << 8) + t;
                const int r = l2 >> 2, u = l2 & 3;
                *((float4*)&slds[r*20 + (u << 2)]) = ep[(rowBase + r)*64 + (c << 2) + u];
            }
            __syncthreads();
            const float* srow = &slds[t*20];
            const int d0 = c << 4;
            #pragma unroll
            for (int j4 = 0; j4 < 4; ++j4) {
                const float4 e4 = *((const float4*)&srow[j4 << 2]);
                #pragma unroll
                for (int u = 0; u < 4; ++u) {
                    const float e = (u==0) ? e4.x : (u==1) ? e4.y : (u==2) ? e4.z : e4.w;
                    const float* gw = &GWg[(size_t)(d0 + (j4 << 2) + u) << 3];  // uniform -> SGPR
                    sum += e;
                    ssq = fmaf(e, e, ssq);
                    S[0] = fmaf(e, gw[0], S[0]); S[1] = fmaf(e, gw[1], S[1]);
                    S[2] = fmaf(e, gw[2], S[2]); S[3] = fmaf(e, gw[3], S[3]);
                    S[4] = fmaf(e, gw[4], S[4]); S[5] = fmaf(e, gw[5], S[5]);
                    S[6] = fmaf(e, gw[6], S[6]); S[7] = fmaf(e, gw[7], S[7]);
                }
            }
            __syncthreads();
        }

        // ---- K chunks: same staging; chunk c belongs to head c>>1 ----
        for (int c = 0; c < 16; ++c) {
            #pragma unroll
            for (int kk = 0; kk < 4; ++kk) {
                const int l2 = (kk << 8) + t;
                const int r = l2 >> 2, u = l2 & 3;
                *((float4*)&slds[r*20 + (u << 2)]) = kg4[(size_t)(krow0 + r)*64 + (c << 2) + u];
            }
            __syncthreads();
            const float* srow = &slds[t*20];
            const float4* q4p = (const float4*)&sqv[c << 4];   // uniform broadcast
            float acc = qk[c >> 1];
            #pragma unroll
            for (int j4 = 0; j4 < 4; ++j4) {
                const float4 k4 = *((const float4*)&srow[j4 << 2]);
                const float4 q4 = q4p[j4];
                acc = fmaf(k4.x, q4.x, acc); acc = fmaf(k4.y, q4.y, acc);
                acc = fmaf(k4.z, q4.z, acc); acc = fmaf(k4.w, q4.w, acc);
            }
            qk[c >> 1] = acc;
            __syncthreads();
        }

        const float m = sum * (1.f/256.f);
        const float rinv = rsqrtf(ssq*(1.f/256.f) - m*m + EPS_);
        const float mb = (msk[rowBase + t] == 0) ? -1e30f : 0.f;
        const int jrow = (half << 8) + t;
        #pragma unroll
        for (int h = 0; h < 8; ++h)
            sb[h*512 + jrow] = qk[h] + rinv * (S[h] - m * Avec[h]) + Cvec[h] + mb;
    }
    __syncthreads();                      // all scores in sb

    // ---- softmax: (h = t>>5, l = t&31) owns keys j in [16l, 16l+16) ----
    {
        const int h = t >> 5, l = t & 31;
        float* base = &sb[h*512 + (l << 4)];
        float4 s4[4];
        float pmax = -3.0e38f;
        #pragma unroll
        for (int i = 0; i < 4; ++i) {
            s4[i] = *((const float4*)&base[i << 2]);
            pmax = fmaxf(pmax, fmaxf(fmaxf(s4[i].x, s4[i].y), fmaxf(s4[i].z, s4[i].w)));
        }
        #pragma unroll
        for (int o = 16; o >= 1; o >>= 1) pmax = fmaxf(pmax, __shfl_xor(pmax, o));
        float psum = 0.f;
        #pragma unroll
        for (int i = 0; i < 4; ++i) {
            const float p0 = __expf(s4[i].x - pmax), p1 = __expf(s4[i].y - pmax);
            const float p2 = __expf(s4[i].z - pmax), p3 = __expf(s4[i].w - pmax);
            psum += (p0 + p1) + (p2 + p3);
            *((float4*)&base[i << 2]) = make_float4(p0, p1, p2, p3);
        }
        #pragma unroll
        for (int o = 16; o >= 1; o >>= 1) psum += __shfl_xor(psum, o);
        if (l == 0) sden[h] = psum;
    }
    __syncthreads();

    // ---- PV: thread t owns output channel t; prob reads are uniform broadcasts ----
    {
        const int h = t >> 5;
        const float* vb = vg + ((size_t)b << 9)*256 + t;
        const float4* spr4 = (const float4*)&sb[h*512];
        float a0 = 0.f, a1 = 0.f, a2 = 0.f, a3 = 0.f;
        for (int j4 = 0; j4 < 128; ++j4) {
            const float4 p4 = spr4[j4];
            const float* vj = vb + ((size_t)j4 << 2)*256;
            a0 = fmaf(p4.x, vj[0],   a0);
            a1 = fmaf(p4.y, vj[256], a1);
            a2 = fmaf(p4.z, vj[512], a2);
            a3 = fmaf(p4.w, vj[768], a3);
        }
        ao[(size_t)bi*256 + t] = (a0+a1+a2+a3) / sden[h];
    }
}

// ---------------- output projection + residual: 2 rows/block, grid 512 ----------------
__global__ __launch_bounds__(256) void k_proj(
    const float* __restrict__ at, const float* __restrict__ Wo,
    const float* __restrict__ bo, const float* __restrict__ x,
    float* __restrict__ x1)
{
    const int t = threadIdx.x;
    const int wid = t >> 6, l = t & 63;
    const int r0 = blockIdx.x << 1;
    __shared__ float saT[256*2];          // [d][row]
    if (wid < 2) {
        const float4 a4 = ((const float4*)at)[(r0 + wid)*64 + l];
        saT[(4*l+0)*2 + wid] = a4.x;
        saT[(4*l+1)*2 + wid] = a4.y;
        saT[(4*l+2)*2 + wid] = a4.z;
        saT[(4*l+3)*2 + wid] = a4.w;
    }
    __syncthreads();
    float A0 = bo[t], A1 = A0;
    for (int d = 0; d < 256; d += 2) {
        const float4 s4 = *((const float4*)&saT[d*2]);
        const float wa = Wo[d*256 + t], wb = Wo[(d+1)*256 + t];
        A0 = fmaf(s4.x, wa, A0); A0 = fmaf(s4.z, wb, A0);
        A1 = fmaf(s4.y, wa, A1); A1 = fmaf(s4.w, wb, A1);
    }
    x1[(r0+0)*256 + t] = A0 + x[(r0+0)*256 + t];
    x1[(r0+1)*256 + t] = A1 + x[(r0+1)*256 + t];
}

// ---------------- FFN: 4 rows/block, grid 256 ----------------
__global__ __launch_bounds__(256) void k_ff(
    const float* __restrict__ x1, const float* __restrict__ g,
    const float* __restrict__ bb,
    const float* __restrict__ W1, const float* __restrict__ b1,
    const float* __restrict__ W2, const float* __restrict__ b2,
    float* __restrict__ out)
{
    const int t = threadIdx.x;
    const int wid = t >> 6, l = t & 63;
    const int r0 = blockIdx.x << 2;
    __shared__ float shT[256*4];          // [d][row] LN values
    __shared__ float sfT[1024*4];         // [dff][row] gelu values
    {
        const int row = r0 + wid;
        const float4 xv4 = ((const float4*)x1)[row*64 + l];
        float s  = xv4.x + xv4.y + xv4.z + xv4.w;
        float q2 = xv4.x*xv4.x + xv4.y*xv4.y + xv4.z*xv4.z + xv4.w*xv4.w;
        #pragma unroll
        for (int o = 32; o >= 1; o >>= 1) { s += __shfl_xor(s, o); q2 += __shfl_xor(q2, o); }
        const float m = s * (1.f/256.f);
        const float rinv = rsqrtf(q2*(1.f/256.f) - m*m + EPS_);
        const float4 g4 = ((const float4*)g)[l];
        const float4 b4 = ((const float4*)bb)[l];
        shT[(4*l+0)*4 + wid] = (xv4.x - m)*rinv*g4.x + b4.x;
        shT[(4*l+1)*4 + wid] = (xv4.y - m)*rinv*g4.y + b4.y;
        shT[(4*l+2)*4 + wid] = (xv4.z - m)*rinv*g4.z + b4.z;
        shT[(4*l+3)*4 + wid] = (xv4.w - m)*rinv*g4.w + b4.w;
    }
    __syncthreads();
    const float4 bc = ((const float4*)b1)[t];
    float4 Ac0 = make_float4(bc.x,bc.x,bc.x,bc.x);
    float4 Ac1 = make_float4(bc.y,bc.y,bc.y,bc.y);
    float4 Ac2 = make_float4(bc.z,bc.z,bc.z,bc.z);
    float4 Ac3 = make_float4(bc.w,bc.w,bc.w,bc.w);
    const float4* W14 = (const float4*)W1;
    for (int d = 0; d < 256; ++d) {
        const float4 s4 = *((const float4*)&shT[d*4]);
        const float4 w4 = W14[d*256 + t];
        Ac0.x = fmaf(s4.x, w4.x, Ac0.x); Ac0.y = fmaf(s4.y, w4.x, Ac0.y);
        Ac0.z = fmaf(s4.z, w4.x, Ac0.z); Ac0.w = fmaf(s4.w, w4.x, Ac0.w);
        Ac1.x = fmaf(s4.x, w4.y, Ac1.x); Ac1.y = fmaf(s4.y, w4.y, Ac1.y);
        Ac1.z = fmaf(s4.z, w4.y, Ac1.z); Ac1.w = fmaf(s4.w, w4.y, Ac1.w);
        Ac2.x = fmaf(s4.x, w4.z, Ac2.x); Ac2.y = fmaf(s4.y, w4.z, Ac2.y);
        Ac2.z = fmaf(s4.z, w4.z, Ac2.z); Ac2.w = fmaf(s4.w, w4.z, Ac2.w);
        Ac3.x = fmaf(s4.x, w4.w, Ac3.x); Ac3.y = fmaf(s4.y, w4.w, Ac3.y);
        Ac3.z = fmaf(s4.z, w4.w, Ac3.z); Ac3.w = fmaf(s4.w, w4.w, Ac3.w);
    }
    *((float4*)&sfT[(4*t+0)*4]) = make_float4(gelu_(Ac0.x), gelu_(Ac0.y), gelu_(Ac0.z), gelu_(Ac0.w));
    *((float4*)&sfT[(4*t+1)*4]) = make_float4(gelu_(Ac1.x), gelu_(Ac1.y), gelu_(Ac1.z), gelu_(Ac1.w));
    *((float4*)&sfT[(4*t+2)*4]) = make_float4(gelu_(Ac2.x), gelu_(Ac2.y), gelu_(Ac2.z), gelu_(Ac2.w));
    *((float4*)&sfT[(4*t+3)*4]) = make_float4(gelu_(Ac3.x), gelu_(Ac3.y), gelu_(Ac3.z), gelu_(Ac3.w));
    __syncthreads();
    const float b2v = b2[t];
    float4 AO = make_float4(b2v,b2v,b2v,b2v);
    for (int kk = 0; kk < 1024; ++kk) {
        const float4 s4 = *((const float4*)&sfT[kk*4]);
        const float w = W2[kk*256 + t];
        AO.x = fmaf(s4.x, w, AO.x); AO.y = fmaf(s4.y, w, AO.y);
        AO.z = fmaf(s4.z, w, AO.z); AO.w = fmaf(s4.w, w, AO.w);
    }
    out[(r0+0)*256 + t] = AO.x + x1[(r0+0)*256 + t];
    out[(r0+1)*256 + t] = AO.y + x1[(r0+1)*256 + t];
    out[(r0+2)*256 + t] = AO.z + x1[(r0+2)*256 + t];
    out[(r0+3)*256 + t] = AO.w + x1[(r0+3)*256 + t];
}

extern "C" void kernel_launch(void* const* d_in, const int* in_sizes, int n_in,
                              void* d_out, int out_size, void* d_ws, size_t ws_size,
                              hipStream_t stream) {
    const float* x   = (const float*)d_in[0];
    const float* ef  = (const float*)d_in[1];
    const int*   am  = (const int*)d_in[2];
    const float* ng  = (const float*)d_in[3];
    const float* nb  = (const float*)d_in[4];
    const float* eg  = (const float*)d_in[5];
    const float* ebb = (const float*)d_in[6];
    const float* Wq  = (const float*)d_in[7];
    const float* bq  = (const float*)d_in[8];
    const float* Wk  = (const float*)d_in[9];
    const float* bk  = (const float*)d_in[10];
    const float* Wv  = (const float*)d_in[11];
    const float* bv  = (const float*)d_in[12];
    const float* Wo  = (const float*)d_in[13];
    const float* bo  = (const float*)d_in[14];
    const float* We  = (const float*)d_in[15];
    const float* be  = (const float*)d_in[16];
    const float* fg  = (const float*)d_in[17];
    const float* fb  = (const float*)d_in[18];
    const float* W1  = (const float*)d_in[19];
    const float* b1  = (const float*)d_in[20];
    const float* W2  = (const float*)d_in[21];
    const float* b2  = (const float*)d_in[22];

    float* ws  = (float*)d_ws;
    float* GW  = ws;                      // 2048 f
    float* Av  = ws + 2048;               // 8 f
    float* Cv  = ws + 2064;               // 8 f
    float* q   = ws + 4096;               // 262144 f (B,N,D)
    float* k   = q  + 262144;
    float* v   = k  + 262144;
    float* ao  = v  + 262144;             // 262144 f (B,N,D)
    float* x1  = ao + 262144;             // 262144 f  -> total ~5.3 MB

    hipLaunchKernelGGL(k_setup, dim3(1), dim3(256), 0, stream, eg, ebb, We, be, GW, Av, Cv);
    hipLaunchKernelGGL(k_qkv, dim3(512), dim3(256), 0, stream,
                       x, ng, nb, Wq, bq, Wk, bk, Wv, bv, q, k, v);
    hipLaunchKernelGGL(k_eattn, dim3(1024), dim3(256), 0, stream,
                       (const float4*)ef, am, GW, Av, Cv, q, (const float4*)k, v, ao);
    hipLaunchKernelGGL(k_proj, dim3(512), dim3(256), 0, stream, ao, Wo, bo, x, x1);
    hipLaunchKernelGGL(k_ff, dim3(256), dim3(256), 0, stream,
                       x1, fg, fb, W1, b1, W2, b2, (float*)d_out);
}

// Round 11
// 291.594 us; speedup vs baseline: 1.1921x; 1.0047x over previous
//
#include <hip/hip_runtime.h>
#include <hip/hip_bf16.h>

typedef unsigned int uint;

// B=2, N=512, D=256, H=8, HD=32, DFF=1024
constexpr float EPS_ = 1e-5f;

#define DEV __device__ __forceinline__

DEV float gelu_(float x){ return 0.5f*x*(1.f + erff(x*0.70710678118654752f)); }

// ---------------- setup: GW[d][h]=g_d*We[d,h], A[h]=sum GW, C[h]=sum b_d*We+be ----------------
__global__ __launch_bounds__(256) void k_setup(
    const float* __restrict__ g, const float* __restrict__ b,
    const float* __restrict__ We, const float* __restrict__ be,
    float* __restrict__ GW, float* __restrict__ A, float* __restrict__ C)
{
    const int d = threadIdx.x;
    __shared__ float redA[256*8];
    __shared__ float redC[256*8];
    float gd = g[d], bd = b[d];
    #pragma unroll
    for (int h = 0; h < 8; ++h) {
        float w = We[d*8+h];
        float gw = gd*w;
        GW[d*8+h] = gw;
        redA[d*8+h] = gw;
        redC[d*8+h] = bd*w;
    }
    __syncthreads();
    for (int s = 128; s >= 1; s >>= 1) {
        if (d < s) {
            #pragma unroll
            for (int h = 0; h < 8; ++h) {
                redA[d*8+h] += redA[(d+s)*8+h];
                redC[d*8+h] += redC[(d+s)*8+h];
            }
        }
        __syncthreads();
    }
    if (d < 8) {
        A[d] = redA[d];
        C[d] = redC[d] + be[d];
    }
}

// ---------------- node LN + QKV: 2 rows/block, grid 512 ----------------
__global__ __launch_bounds__(256) void k_qkv(
    const float* __restrict__ x,
    const float* __restrict__ g, const float* __restrict__ bta,
    const float* __restrict__ Wq, const float* __restrict__ bq,
    const float* __restrict__ Wk, const float* __restrict__ bk,
    const float* __restrict__ Wv, const float* __restrict__ bv,
    float* __restrict__ q, float* __restrict__ k, float* __restrict__ v)
{
    const int t = threadIdx.x;
    const int wid = t >> 6, l = t & 63;
    const int r0 = blockIdx.x << 1;
    __shared__ float sxT[256*2];          // [d][row]
    if (wid < 2) {
        const int row = r0 + wid;
        const float4 xv4 = ((const float4*)x)[row*64 + l];
        float s  = xv4.x + xv4.y + xv4.z + xv4.w;
        float q2 = xv4.x*xv4.x + xv4.y*xv4.y + xv4.z*xv4.z + xv4.w*xv4.w;
        #pragma unroll
        for (int o = 32; o >= 1; o >>= 1) { s += __shfl_xor(s, o); q2 += __shfl_xor(q2, o); }
        const float m = s * (1.f/256.f);
        const float rinv = rsqrtf(q2*(1.f/256.f) - m*m + EPS_);
        const float4 g4 = ((const float4*)g)[l];
        const float4 b4 = ((const float4*)bta)[l];
        sxT[(4*l+0)*2 + wid] = (xv4.x - m)*rinv*g4.x + b4.x;
        sxT[(4*l+1)*2 + wid] = (xv4.y - m)*rinv*g4.y + b4.y;
        sxT[(4*l+2)*2 + wid] = (xv4.z - m)*rinv*g4.z + b4.z;
        sxT[(4*l+3)*2 + wid] = (xv4.w - m)*rinv*g4.w + b4.w;
    }
    __syncthreads();
    float aq0 = bq[t], ak0 = bk[t], av0 = bv[t];
    float aq1 = aq0, ak1 = ak0, av1 = av0;
    for (int d = 0; d < 256; d += 2) {
        const float4 s4 = *((const float4*)&sxT[d*2]);
        const float wqa = Wq[d*256 + t], wqb = Wq[(d+1)*256 + t];
        const float wka = Wk[d*256 + t], wkb = Wk[(d+1)*256 + t];
        const float wva = Wv[d*256 + t], wvb = Wv[(d+1)*256 + t];
        aq0 = fmaf(s4.x, wqa, aq0); aq0 = fmaf(s4.z, wqb, aq0);
        aq1 = fmaf(s4.y, wqa, aq1); aq1 = fmaf(s4.w, wqb, aq1);
        ak0 = fmaf(s4.x, wka, ak0); ak0 = fmaf(s4.z, wkb, ak0);
        ak1 = fmaf(s4.y, wka, ak1); ak1 = fmaf(s4.w, wkb, ak1);
        av0 = fmaf(s4.x, wva, av0); av0 = fmaf(s4.z, wvb, av0);
        av1 = fmaf(s4.y, wva, av1); av1 = fmaf(s4.w, wvb, av1);
    }
    q[(r0+0)*256 + t] = aq0; q[(r0+1)*256 + t] = aq1;
    k[(r0+0)*256 + t] = ak0; k[(r0+1)*256 + t] = ak1;
    v[(r0+0)*256 + t] = av0; v[(r0+1)*256 + t] = av1;
}

// ---------------- fused: edge LN bias + QK^T + softmax + PV for one (b,i) ----------------
// T14 async-STAGE pipeline: chunk c+1 global->regs issued before compute of chunk c;
// ds_write at top of next iteration. Loads-to-regs survive __syncthreads (no vmcnt drain).
__global__ __launch_bounds__(256) void k_eattn(
    const float4* __restrict__ ep,        // edge as float4: 64 per 256-elem row
    const int*   __restrict__ msk,        // (B,N,N)
    const float* __restrict__ GWg, const float* __restrict__ Avec, const float* __restrict__ Cvec,
    const float* __restrict__ qg, const float4* __restrict__ kg4, const float* __restrict__ vg,
    float* __restrict__ ao)               // (B,N,D) f32
{
    __shared__ float slds[256*20];        // 20480 B staging (stride 20: conflict-free b128)
    __shared__ float sb[8*512];           // [h][j] scores -> probs in place, 16 KB
    __shared__ float sqv[256];            // q row, pre-scaled
    __shared__ float sden[8];
    const int t = threadIdx.x;
    const int bi = blockIdx.x;            // b*512 + i
    const int b = bi >> 9;
    sqv[t] = qg[(size_t)bi*256 + t] * 0.17677669529663687f;   // 1/sqrt(32)
    __syncthreads();

    const int r = t >> 2, u = t & 3;      // staging coords: this thread writes rows {r, r+64, r+128, r+192}

    for (int half = 0; half < 2; ++half) {
        const long long rowBase = ((long long)bi << 9) + (half << 8);   // edge row (b,i,j0)
        const int krow0 = (b << 9) + (half << 8);                       // key row (b,j0)
        float sum = 0.f, ssq = 0.f;
        float S[8]  = {0.f,0.f,0.f,0.f,0.f,0.f,0.f,0.f};
        float qk[8] = {0.f,0.f,0.f,0.f,0.f,0.f,0.f,0.f};

        // 32 chunks: cc<16 -> edge chunk cc; cc>=16 -> K chunk cc-16
        float4 R0, R1, R2, R3;
        {   // prologue: chunk 0 (edge)
            R0 = ep[(rowBase + r      )*64 + u];
            R1 = ep[(rowBase + r +  64)*64 + u];
            R2 = ep[(rowBase + r + 128)*64 + u];
            R3 = ep[(rowBase + r + 192)*64 + u];
        }
        for (int cc = 0; cc < 32; ++cc) {
            // write prefetched chunk cc (compiler inserts vmcnt wait)
            *((float4*)&slds[(r      )*20 + (u << 2)]) = R0;
            *((float4*)&slds[(r +  64)*20 + (u << 2)]) = R1;
            *((float4*)&slds[(r + 128)*20 + (u << 2)]) = R2;
            *((float4*)&slds[(r + 192)*20 + (u << 2)]) = R3;
            __syncthreads();
            // issue chunk cc+1 loads into regs (in flight during compute)
            if (cc + 1 < 32) {
                const int nc = cc + 1;
                if (nc < 16) {
                    R0 = ep[(rowBase + r      )*64 + (nc << 2) + u];
                    R1 = ep[(rowBase + r +  64)*64 + (nc << 2) + u];
                    R2 = ep[(rowBase + r + 128)*64 + (nc << 2) + u];
                    R3 = ep[(rowBase + r + 192)*64 + (nc << 2) + u];
                } else {
                    const int kc = nc - 16;
                    R0 = kg4[(size_t)(krow0 + r      )*64 + (kc << 2) + u];
                    R1 = kg4[(size_t)(krow0 + r +  64)*64 + (kc << 2) + u];
                    R2 = kg4[(size_t)(krow0 + r + 128)*64 + (kc << 2) + u];
                    R3 = kg4[(size_t)(krow0 + r + 192)*64 + (kc << 2) + u];
                }
            }
            // compute chunk cc from LDS
            const float* srow = &slds[t*20];
            if (cc < 16) {
                const int d0 = cc << 4;
                #pragma unroll
                for (int j4 = 0; j4 < 4; ++j4) {
                    const float4 e4 = *((const float4*)&srow[j4 << 2]);
                    #pragma unroll
                    for (int uu = 0; uu < 4; ++uu) {
                        const float e = (uu==0) ? e4.x : (uu==1) ? e4.y : (uu==2) ? e4.z : e4.w;
                        const float* gw = &GWg[(size_t)(d0 + (j4 << 2) + uu) << 3];  // uniform -> SGPR
                        sum += e;
                        ssq = fmaf(e, e, ssq);
                        S[0] = fmaf(e, gw[0], S[0]); S[1] = fmaf(e, gw[1], S[1]);
                        S[2] = fmaf(e, gw[2], S[2]); S[3] = fmaf(e, gw[3], S[3]);
                        S[4] = fmaf(e, gw[4], S[4]); S[5] = fmaf(e, gw[5], S[5]);
                        S[6] = fmaf(e, gw[6], S[6]); S[7] = fmaf(e, gw[7], S[7]);
                    }
                }
            } else {
                const int kc = cc - 16;
                const float4* q4p = (const float4*)&sqv[kc << 4];   // uniform broadcast
                float acc = qk[kc >> 1];
                #pragma unroll
                for (int j4 = 0; j4 < 4; ++j4) {
                    const float4 k4 = *((const float4*)&srow[j4 << 2]);
                    const float4 q4 = q4p[j4];
                    acc = fmaf(k4.x, q4.x, acc); acc = fmaf(k4.y, q4.y, acc);
                    acc = fmaf(k4.z, q4.z, acc); acc = fmaf(k4.w, q4.w, acc);
                }
                qk[kc >> 1] = acc;
            }
            __syncthreads();   // readers done before next overwrite
        }

        const float m = sum * (1.f/256.f);
        const float rinv = rsqrtf(ssq*(1.f/256.f) - m*m + EPS_);
        const float mb = (msk[rowBase + t] == 0) ? -1e30f : 0.f;
        const int jrow = (half << 8) + t;
        #pragma unroll
        for (int h = 0; h < 8; ++h)
            sb[h*512 + jrow] = qk[h] + rinv * (S[h] - m * Avec[h]) + Cvec[h] + mb;
        __syncthreads();
    }

    // ---- softmax: (h = t>>5, l = t&31) owns keys j in [16l, 16l+16) ----
    {
        const int h = t >> 5, l = t & 31;
        float* base = &sb[h*512 + (l << 4)];
        float4 s4[4];
        float pmax = -3.0e38f;
        #pragma unroll
        for (int i = 0; i < 4; ++i) {
            s4[i] = *((const float4*)&base[i << 2]);
            pmax = fmaxf(pmax, fmaxf(fmaxf(s4[i].x, s4[i].y), fmaxf(s4[i].z, s4[i].w)));
        }
        #pragma unroll
        for (int o = 16; o >= 1; o >>= 1) pmax = fmaxf(pmax, __shfl_xor(pmax, o));
        float psum = 0.f;
        #pragma unroll
        for (int i = 0; i < 4; ++i) {
            const float p0 = __expf(s4[i].x - pmax), p1 = __expf(s4[i].y - pmax);
            const float p2 = __expf(s4[i].z - pmax), p3 = __expf(s4[i].w - pmax);
            psum += (p0 + p1) + (p2 + p3);
            *((float4*)&base[i << 2]) = make_float4(p0, p1, p2, p3);
        }
        #pragma unroll
        for (int o = 16; o >= 1; o >>= 1) psum += __shfl_xor(psum, o);
        if (l == 0) sden[h] = psum;
    }
    __syncthreads();

    // ---- PV: thread t owns output channel t; prob reads are uniform broadcasts ----
    {
        const int h = t >> 5;
        const float* vb = vg + ((size_t)b << 9)*256 + t;
        const float4* spr4 = (const float4*)&sb[h*512];
        float a0 = 0.f, a1 = 0.f, a2 = 0.f, a3 = 0.f;
        for (int j4 = 0; j4 < 128; ++j4) {
            const float4 p4 = spr4[j4];
            const float* vj = vb + ((size_t)j4 << 2)*256;
            a0 = fmaf(p4.x, vj[0],   a0);
            a1 = fmaf(p4.y, vj[256], a1);
            a2 = fmaf(p4.z, vj[512], a2);
            a3 = fmaf(p4.w, vj[768], a3);
        }
        ao[(size_t)bi*256 + t] = (a0+a1+a2+a3) / sden[h];
    }
}

// ---------------- output projection + residual: 2 rows/block, grid 512 ----------------
__global__ __launch_bounds__(256) void k_proj(
    const float* __restrict__ at, const float* __restrict__ Wo,
    const float* __restrict__ bo, const float* __restrict__ x,
    float* __restrict__ x1)
{
    const int t = threadIdx.x;
    const int wid = t >> 6, l = t & 63;
    const int r0 = blockIdx.x << 1;
    __shared__ float saT[256*2];          // [d][row]
    if (wid < 2) {
        const float4 a4 = ((const float4*)at)[(r0 + wid)*64 + l];
        saT[(4*l+0)*2 + wid] = a4.x;
        saT[(4*l+1)*2 + wid] = a4.y;
        saT[(4*l+2)*2 + wid] = a4.z;
        saT[(4*l+3)*2 + wid] = a4.w;
    }
    __syncthreads();
    float A0 = bo[t], A1 = A0;
    for (int d = 0; d < 256; d += 2) {
        const float4 s4 = *((const float4*)&saT[d*2]);
        const float wa = Wo[d*256 + t], wb = Wo[(d+1)*256 + t];
        A0 = fmaf(s4.x, wa, A0); A0 = fmaf(s4.z, wb, A0);
        A1 = fmaf(s4.y, wa, A1); A1 = fmaf(s4.w, wb, A1);
    }
    x1[(r0+0)*256 + t] = A0 + x[(r0+0)*256 + t];
    x1[(r0+1)*256 + t] = A1 + x[(r0+1)*256 + t];
}

// ---------------- FFN: 4 rows/block, grid 256 ----------------
__global__ __launch_bounds__(256) void k_ff(
    const float* __restrict__ x1, const float* __restrict__ g,
    const float* __restrict__ bb,
    const float* __restrict__ W1, const float* __restrict__ b1,
    const float* __restrict__ W2, const float* __restrict__ b2,
    float* __restrict__ out)
{
    const int t = threadIdx.x;
    const int wid = t >> 6, l = t & 63;
    const int r0 = blockIdx.x << 2;
    __shared__ float shT[256*4];          // [d][row] LN values
    __shared__ float sfT[1024*4];         // [dff][row] gelu values
    {
        const int row = r0 + wid;
        const float4 xv4 = ((const float4*)x1)[row*64 + l];
        float s  = xv4.x + xv4.y + xv4.z + xv4.w;
        float q2 = xv4.x*xv4.x + xv4.y*xv4.y + xv4.z*xv4.z + xv4.w*xv4.w;
        #pragma unroll
        for (int o = 32; o >= 1; o >>= 1) { s += __shfl_xor(s, o); q2 += __shfl_xor(q2, o); }
        const float m = s * (1.f/256.f);
        const float rinv = rsqrtf(q2*(1.f/256.f) - m*m + EPS_);
        const float4 g4 = ((const float4*)g)[l];
        const float4 b4 = ((const float4*)bb)[l];
        shT[(4*l+0)*4 + wid] = (xv4.x - m)*rinv*g4.x + b4.x;
        shT[(4*l+1)*4 + wid] = (xv4.y - m)*rinv*g4.y + b4.y;
        shT[(4*l+2)*4 + wid] = (xv4.z - m)*rinv*g4.z + b4.z;
        shT[(4*l+3)*4 + wid] = (xv4.w - m)*rinv*g4.w + b4.w;
    }
    __syncthreads();
    const float4 bc = ((const float4*)b1)[t];
    float4 Ac0 = make_float4(bc.x,bc.x,bc.x,bc.x);
    float4 Ac1 = make_float4(bc.y,bc.y,bc.y,bc.y);
    float4 Ac2 = make_float4(bc.z,bc.z,bc.z,bc.z);
    float4 Ac3 = make_float4(bc.w,bc.w,bc.w,bc.w);
    const float4* W14 = (const float4*)W1;
    for (int d = 0; d < 256; ++d) {
        const float4 s4 = *((const float4*)&shT[d*4]);
        const float4 w4 = W14[d*256 + t];
        Ac0.x = fmaf(s4.x, w4.x, Ac0.x); Ac0.y = fmaf(s4.y, w4.x, Ac0.y);
        Ac0.z = fmaf(s4.z, w4.x, Ac0.z); Ac0.w = fmaf(s4.w, w4.x, Ac0.w);
        Ac1.x = fmaf(s4.x, w4.y, Ac1.x); Ac1.y = fmaf(s4.y, w4.y, Ac1.y);
        Ac1.z = fmaf(s4.z, w4.y, Ac1.z); Ac1.w = fmaf(s4.w, w4.y, Ac1.w);
        Ac2.x = fmaf(s4.x, w4.z, Ac2.x); Ac2.y = fmaf(s4.y, w4.z, Ac2.y);
        Ac2.z = fmaf(s4.z, w4.z, Ac2.z); Ac2.w = fmaf(s4.w, w4.z, Ac2.w);
        Ac3.x = fmaf(s4.x, w4.w, Ac3.x); Ac3.y = fmaf(s4.y, w4.w, Ac3.y);
        Ac3.z = fmaf(s4.z, w4.w, Ac3.z); Ac3.w = fmaf(s4.w, w4.w, Ac3.w);
    }
    *((float4*)&sfT[(4*t+0)*4]) = make_float4(gelu_(Ac0.x), gelu_(Ac0.y), gelu_(Ac0.z), gelu_(Ac0.w));
    *((float4*)&sfT[(4*t+1)*4]) = make_float4(gelu_(Ac1.x), gelu_(Ac1.y), gelu_(Ac1.z), gelu_(Ac1.w));
    *((float4*)&sfT[(4*t+2)*4]) = make_float4(gelu_(Ac2.x), gelu_(Ac2.y), gelu_(Ac2.z), gelu_(Ac2.w));
    *((float4*)&sfT[(4*t+3)*4]) = make_float4(gelu_(Ac3.x), gelu_(Ac3.y), gelu_(Ac3.z), gelu_(Ac3.w));
    __syncthreads();
    const float b2v = b2[t];
    float4 AO = make_float4(b2v,b2v,b2v,b2v);
    for (int kk = 0; kk < 1024; ++kk) {
        const float4 s4 = *((const float4*)&sfT[kk*4]);
        const float w = W2[kk*256 + t];
        AO.x = fmaf(s4.x, w, AO.x); AO.y = fmaf(s4.y, w, AO.y);
        AO.z = fmaf(s4.z, w, AO.z); AO.w = fmaf(s4.w, w, AO.w);
    }
    out[(r0+0)*256 + t] = AO.x + x1[(r0+0)*256 + t];
    out[(r0+1)*256 + t] = AO.y + x1[(r0+1)*256 + t];
    out[(r0+2)*256 + t] = AO.z + x1[(r0+2)*256 + t];
    out[(r0+3)*256 + t] = AO.w + x1[(r0+3)*256 + t];
}

extern "C" void kernel_launch(void* const* d_in, const int* in_sizes, int n_in,
                              void* d_out, int out_size, void* d_ws, size_t ws_size,
                              hipStream_t stream) {
    const float* x   = (const float*)d_in[0];
    const float* ef  = (const float*)d_in[1];
    const int*   am  = (const int*)d_in[2];
    const float* ng  = (const float*)d_in[3];
    const float* nb  = (const float*)d_in[4];
    const float* eg  = (const float*)d_in[5];
    const float* ebb = (const float*)d_in[6];
    const float* Wq  = (const float*)d_in[7];
    const float* bq  = (const float*)d_in[8];
    const float* Wk  = (const float*)d_in[9];
    const float* bk  = (const float*)d_in[10];
    const float* Wv  = (const float*)d_in[11];
    const float* bv  = (const float*)d_in[12];
    const float* Wo  = (const float*)d_in[13];
    const float* bo  = (const float*)d_in[14];
    const float* We  = (const float*)d_in[15];
    const float* be  = (const float*)d_in[16];
    const float* fg  = (const float*)d_in[17];
    const float* fb  = (const float*)d_in[18];
    const float* W1  = (const float*)d_in[19];
    const float* b1  = (const float*)d_in[20];
    const float* W2  = (const float*)d_in[21];
    const float* b2  = (const float*)d_in[22];

    float* ws  = (float*)d_ws;
    float* GW  = ws;                      // 2048 f
    float* Av  = ws + 2048;               // 8 f
    float* Cv  = ws + 2064;               // 8 f
    float* q   = ws + 4096;               // 262144 f (B,N,D)
    float* k   = q  + 262144;
    float* v   = k  + 262144;
    float* ao  = v  + 262144;             // 262144 f (B,N,D)
    float* x1  = ao + 262144;             // 262144 f  -> total ~5.3 MB

    hipLaunchKernelGGL(k_setup, dim3(1), dim3(256), 0, stream, eg, ebb, We, be, GW, Av, Cv);
    hipLaunchKernelGGL(k_qkv, dim3(512), dim3(256), 0, stream,
                       x, ng, nb, Wq, bq, Wk, bk, Wv, bv, q, k, v);
    hipLaunchKernelGGL(k_eattn, dim3(1024), dim3(256), 0, stream,
                       (const float4*)ef, am, GW, Av, Cv, q, (const float4*)k, v, ao);
    hipLaunchKernelGGL(k_proj, dim3(512), dim3(256), 0, stream, ao, Wo, bo, x, x1);
    hipLaunchKernelGGL(k_ff, dim3(256), dim3(256), 0, stream,
                       x1, fg, fb, W1, b1, W2, b2, (float*)d_out);
}

// Round 13
// 271.230 us; speedup vs baseline: 1.2816x; 1.0751x over previous
//
#include <hip/hip_runtime.h>
#include <hip/hip_bf16.h>

typedef unsigned int uint;

// B=2, N=512, D=256, H=8, HD=32, DFF=1024
constexpr float EPS_ = 1e-5f;

#define DEV __device__ __forceinline__

DEV float gelu_(float x){ return 0.5f*x*(1.f + erff(x*0.70710678118654752f)); }

// ---------------- node LN + QKV: 2 rows/block, grid 512; block 0 also does edge-bias setup ----------------
__global__ __launch_bounds__(256) void k_qkv(
    const float* __restrict__ x,
    const float* __restrict__ g, const float* __restrict__ bta,
    const float* __restrict__ Wq, const float* __restrict__ bq,
    const float* __restrict__ Wk, const float* __restrict__ bk,
    const float* __restrict__ Wv, const float* __restrict__ bv,
    const float* __restrict__ eg, const float* __restrict__ ebb,
    const float* __restrict__ We, const float* __restrict__ be,
    float* __restrict__ GW, float* __restrict__ Av, float* __restrict__ Cv,
    float* __restrict__ q, float* __restrict__ k, float* __restrict__ v)
{
    const int t = threadIdx.x;
    __shared__ float redA2[4][8];
    __shared__ float redC2[4][8];
    if (blockIdx.x == 0) {
        // setup: GW[d][h]=eg_d*We[d,h]; Av[h]=sum_d GW; Cv[h]=sum_d ebb_d*We + be
        float gd = eg[t], bd = ebb[t];
        float a_loc[8], c_loc[8];
        #pragma unroll
        for (int h = 0; h < 8; ++h) {
            float w = We[t*8 + h];
            float gw = gd * w;
            GW[t*8 + h] = gw;
            a_loc[h] = gw;
            c_loc[h] = bd * w;
        }
        #pragma unroll
        for (int h = 0; h < 8; ++h) {
            #pragma unroll
            for (int o = 32; o >= 1; o >>= 1) {
                a_loc[h] += __shfl_xor(a_loc[h], o);
                c_loc[h] += __shfl_xor(c_loc[h], o);
            }
        }
        if ((t & 63) == 0) {
            const int w = t >> 6;
            #pragma unroll
            for (int h = 0; h < 8; ++h) { redA2[w][h] = a_loc[h]; redC2[w][h] = c_loc[h]; }
        }
        __syncthreads();
        if (t < 8) {
            Av[t] = redA2[0][t] + redA2[1][t] + redA2[2][t] + redA2[3][t];
            Cv[t] = redC2[0][t] + redC2[1][t] + redC2[2][t] + redC2[3][t] + be[t];
        }
    }

    const int wid = t >> 6, l = t & 63;
    const int r0 = blockIdx.x << 1;
    __shared__ float sxT[256*2];          // [d][row]
    if (wid < 2) {
        const int row = r0 + wid;
        const float4 xv4 = ((const float4*)x)[row*64 + l];
        float s  = xv4.x + xv4.y + xv4.z + xv4.w;
        float q2 = xv4.x*xv4.x + xv4.y*xv4.y + xv4.z*xv4.z + xv4.w*xv4.w;
        #pragma unroll
        for (int o = 32; o >= 1; o >>= 1) { s += __shfl_xor(s, o); q2 += __shfl_xor(q2, o); }
        const float m = s * (1.f/256.f);
        const float rinv = rsqrtf(q2*(1.f/256.f) - m*m + EPS_);
        const float4 g4 = ((const float4*)g)[l];
        const float4 b4 = ((const float4*)bta)[l];
        sxT[(4*l+0)*2 + wid] = (xv4.x - m)*rinv*g4.x + b4.x;
        sxT[(4*l+1)*2 + wid] = (xv4.y - m)*rinv*g4.y + b4.y;
        sxT[(4*l+2)*2 + wid] = (xv4.z - m)*rinv*g4.z + b4.z;
        sxT[(4*l+3)*2 + wid] = (xv4.w - m)*rinv*g4.w + b4.w;
    }
    __syncthreads();
    float aq0 = bq[t], ak0 = bk[t], av0 = bv[t];
    float aq1 = aq0, ak1 = ak0, av1 = av0;
    for (int d = 0; d < 256; d += 2) {
        const float4 s4 = *((const float4*)&sxT[d*2]);
        const float wqa = Wq[d*256 + t], wqb = Wq[(d+1)*256 + t];
        const float wka = Wk[d*256 + t], wkb = Wk[(d+1)*256 + t];
        const float wva = Wv[d*256 + t], wvb = Wv[(d+1)*256 + t];
        aq0 = fmaf(s4.x, wqa, aq0); aq0 = fmaf(s4.z, wqb, aq0);
        aq1 = fmaf(s4.y, wqa, aq1); aq1 = fmaf(s4.w, wqb, aq1);
        ak0 = fmaf(s4.x, wka, ak0); ak0 = fmaf(s4.z, wkb, ak0);
        ak1 = fmaf(s4.y, wka, ak1); ak1 = fmaf(s4.w, wkb, ak1);
        av0 = fmaf(s4.x, wva, av0); av0 = fmaf(s4.z, wvb, av0);
        av1 = fmaf(s4.y, wva, av1); av1 = fmaf(s4.w, wvb, av1);
    }
    q[(r0+0)*256 + t] = aq0; q[(r0+1)*256 + t] = aq1;
    k[(r0+0)*256 + t] = ak0; k[(r0+1)*256 + t] = ak1;
    v[(r0+0)*256 + t] = av0; v[(r0+1)*256 + t] = av1;
}

// ---------------- fused: edge LN bias + QK^T + softmax + PV for one (b,i) ----------------
// LDS union: staging buffer (20KB) and score buffer (16KB) share smem — disjoint
// lifetimes (half-0 partials held in registers). ~21.5 KB LDS -> 5+ blocks/CU.
__global__ __launch_bounds__(256, 5) void k_eattn(
    const float4* __restrict__ ep,        // edge as float4: 64 per 256-elem row
    const int*   __restrict__ msk,        // (B,N,N)
    const float* __restrict__ GWg, const float* __restrict__ Avec, const float* __restrict__ Cvec,
    const float* __restrict__ qg, const float4* __restrict__ kg4, const float* __restrict__ vg,
    float* __restrict__ ao)               // (B,N,D) f32
{
    __shared__ float smem[5120];          // slds (256*20) ∪ sb (4096)
    __shared__ float sqv[256];            // q row, pre-scaled
    __shared__ float sden[8];
    const int t = threadIdx.x;
    const int bi = blockIdx.x;            // b*512 + i
    const int b = bi >> 9;
    sqv[t] = qg[(size_t)bi*256 + t] * 0.17677669529663687f;   // 1/sqrt(32)
    __syncthreads();

    const int r = t >> 2, u = t & 3;      // staging coords

    float S[2][8], qk[2][8], mval[2], rinv[2], mb[2];

    #pragma unroll
    for (int half = 0; half < 2; ++half) {
        const long long rowBase = ((long long)bi << 9) + (half << 8);   // edge row (b,i,j0)
        const int krow0 = (b << 9) + (half << 8);                       // key row (b,j0)
        float sum = 0.f, ssq = 0.f;
        #pragma unroll
        for (int h = 0; h < 8; ++h) { S[half][h] = 0.f; qk[half][h] = 0.f; }

        // ---- edge chunks: 16 x 16 floats per row ----
        for (int c = 0; c < 16; ++c) {
            *((float4*)&smem[(r      )*20 + (u << 2)]) = ep[(rowBase + r      )*64 + (c << 2) + u];
            *((float4*)&smem[(r +  64)*20 + (u << 2)]) = ep[(rowBase + r +  64)*64 + (c << 2) + u];
            *((float4*)&smem[(r + 128)*20 + (u << 2)]) = ep[(rowBase + r + 128)*64 + (c << 2) + u];
            *((float4*)&smem[(r + 192)*20 + (u << 2)]) = ep[(rowBase + r + 192)*64 + (c << 2) + u];
            __syncthreads();
            const float* srow = &smem[t*20];
            const int d0 = c << 4;
            #pragma unroll
            for (int j4 = 0; j4 < 4; ++j4) {
                const float4 e4 = *((const float4*)&srow[j4 << 2]);
                #pragma unroll
                for (int uu = 0; uu < 4; ++uu) {
                    const float e = (uu==0) ? e4.x : (uu==1) ? e4.y : (uu==2) ? e4.z : e4.w;
                    const float* gw = &GWg[(size_t)(d0 + (j4 << 2) + uu) << 3];  // uniform -> SGPR
                    sum += e;
                    ssq = fmaf(e, e, ssq);
                    S[half][0] = fmaf(e, gw[0], S[half][0]); S[half][1] = fmaf(e, gw[1], S[half][1]);
                    S[half][2] = fmaf(e, gw[2], S[half][2]); S[half][3] = fmaf(e, gw[3], S[half][3]);
                    S[half][4] = fmaf(e, gw[4], S[half][4]); S[half][5] = fmaf(e, gw[5], S[half][5]);
                    S[half][6] = fmaf(e, gw[6], S[half][6]); S[half][7] = fmaf(e, gw[7], S[half][7]);
                }
            }
            __syncthreads();
        }

        // ---- K chunks: 16 x 16 floats per row; chunk c belongs to head c>>1 ----
        for (int c = 0; c < 16; ++c) {
            *((float4*)&smem[(r      )*20 + (u << 2)]) = kg4[(size_t)(krow0 + r      )*64 + (c << 2) + u];
            *((float4*)&smem[(r +  64)*20 + (u << 2)]) = kg4[(size_t)(krow0 + r +  64)*64 + (c << 2) + u];
            *((float4*)&smem[(r + 128)*20 + (u << 2)]) = kg4[(size_t)(krow0 + r + 128)*64 + (c << 2) + u];
            *((float4*)&smem[(r + 192)*20 + (u << 2)]) = kg4[(size_t)(krow0 + r + 192)*64 + (c << 2) + u];
            __syncthreads();
            const float* srow = &smem[t*20];
            const float4* q4p = (const float4*)&sqv[c << 4];   // uniform broadcast
            float acc = qk[half][c >> 1];
            #pragma unroll
            for (int j4 = 0; j4 < 4; ++j4) {
                const float4 k4 = *((const float4*)&srow[j4 << 2]);
                const float4 q4 = q4p[j4];
                acc = fmaf(k4.x, q4.x, acc); acc = fmaf(k4.y, q4.y, acc);
                acc = fmaf(k4.z, q4.z, acc); acc = fmaf(k4.w, q4.w, acc);
            }
            qk[half][c >> 1] = acc;
            __syncthreads();
        }

        mval[half] = sum * (1.f/256.f);
        rinv[half] = rsqrtf(ssq*(1.f/256.f) - mval[half]*mval[half] + EPS_);
        mb[half]   = (msk[rowBase + t] == 0) ? -1e30f : 0.f;
    }

    // ---- write scores into sb (aliases smem; staging is dead now) ----
    float* sb = smem;
    #pragma unroll
    for (int half = 0; half < 2; ++half) {
        const int jrow = (half << 8) + t;
        #pragma unroll
        for (int h = 0; h < 8; ++h)
            sb[h*512 + jrow] = qk[half][h]
                             + rinv[half] * (S[half][h] - mval[half] * Avec[h])
                             + Cvec[h] + mb[half];
    }
    __syncthreads();

    // ---- softmax: (h = t>>5, l = t&31) owns keys j in [16l, 16l+16) ----
    {
        const int h = t >> 5, l = t & 31;
        float* base = &sb[h*512 + (l << 4)];
        float4 s4[4];
        float pmax = -3.0e38f;
        #pragma unroll
        for (int i = 0; i < 4; ++i) {
            s4[i] = *((const float4*)&base[i << 2]);
            pmax = fmaxf(pmax, fmaxf(fmaxf(s4[i].x, s4[i].y), fmaxf(s4[i].z, s4[i].w)));
        }
        #pragma unroll
        for (int o = 16; o >= 1; o >>= 1) pmax = fmaxf(pmax, __shfl_xor(pmax, o));
        float psum = 0.f;
        #pragma unroll
        for (int i = 0; i < 4; ++i) {
            const float p0 = __expf(s4[i].x - pmax), p1 = __expf(s4[i].y - pmax);
            const float p2 = __expf(s4[i].z - pmax), p3 = __expf(s4[i].w - pmax);
            psum += (p0 + p1) + (p2 + p3);
            *((float4*)&base[i << 2]) = make_float4(p0, p1, p2, p3);
        }
        #pragma unroll
        for (int o = 16; o >= 1; o >>= 1) psum += __shfl_xor(psum, o);
        if (l == 0) sden[h] = psum;
    }
    __syncthreads();

    // ---- PV: thread t owns output channel t; prob reads are uniform broadcasts ----
    {
        const int h = t >> 5;
        const float* vb = vg + ((size_t)b << 9)*256 + t;
        const float4* spr4 = (const float4*)&sb[h*512];
        float a0 = 0.f, a1 = 0.f, a2 = 0.f, a3 = 0.f;
        for (int j4 = 0; j4 < 128; ++j4) {
            const float4 p4 = spr4[j4];
            const float* vj = vb + ((size_t)j4 << 2)*256;
            a0 = fmaf(p4.x, vj[0],   a0);
            a1 = fmaf(p4.y, vj[256], a1);
            a2 = fmaf(p4.z, vj[512], a2);
            a3 = fmaf(p4.w, vj[768], a3);
        }
        ao[(size_t)bi*256 + t] = (a0+a1+a2+a3) / sden[h];
    }
}

// ---------------- fused: output projection + residual + FFN: 2 rows/block, grid 512 ----------------
__global__ __launch_bounds__(256) void k_projff(
    const float* __restrict__ at, const float* __restrict__ Wo,
    const float* __restrict__ bo, const float* __restrict__ x,
    const float* __restrict__ g, const float* __restrict__ bb,
    const float* __restrict__ W1, const float* __restrict__ b1,
    const float* __restrict__ W2, const float* __restrict__ b2,
    float* __restrict__ out)
{
    const int t = threadIdx.x;
    const int wid = t >> 6, l = t & 63;
    const int r0 = blockIdx.x << 1;
    __shared__ float saT[256*2];          // [d][row] attn-out transposed
    __shared__ float shT[256*2];          // [d][row] LN values
    __shared__ float sfT[2*1024];         // [row][dff] gelu values
    __shared__ float sx1[2][256];         // x1 rows (residual + LN input)

    if (wid < 2) {
        const float4 a4 = ((const float4*)at)[(r0 + wid)*64 + l];
        saT[(4*l+0)*2 + wid] = a4.x;
        saT[(4*l+1)*2 + wid] = a4.y;
        saT[(4*l+2)*2 + wid] = a4.z;
        saT[(4*l+3)*2 + wid] = a4.w;
    }
    __syncthreads();
    // proj + residual -> x1 in LDS
    {
        float A0 = bo[t], A1 = A0;
        for (int d = 0; d < 256; d += 2) {
            const float4 s4 = *((const float4*)&saT[d*2]);
            const float wa = Wo[d*256 + t], wb = Wo[(d+1)*256 + t];
            A0 = fmaf(s4.x, wa, A0); A0 = fmaf(s4.z, wb, A0);
            A1 = fmaf(s4.y, wa, A1); A1 = fmaf(s4.w, wb, A1);
        }
        sx1[0][t] = A0 + x[(r0+0)*256 + t];
        sx1[1][t] = A1 + x[(r0+1)*256 + t];
    }
    __syncthreads();
    // LN of x1 rows (waves 0,1), transposed into shT
    if (wid < 2) {
        const float4 xv4 = *((const float4*)&sx1[wid][4*l]);
        float s  = xv4.x + xv4.y + xv4.z + xv4.w;
        float q2 = xv4.x*xv4.x + xv4.y*xv4.y + xv4.z*xv4.z + xv4.w*xv4.w;
        #pragma unroll
        for (int o = 32; o >= 1; o >>= 1) { s += __shfl_xor(s, o); q2 += __shfl_xor(q2, o); }
        const float m = s * (1.f/256.f);
        const float rinv = rsqrtf(q2*(1.f/256.f) - m*m + EPS_);
        const float4 g4 = ((const float4*)g)[l];
        const float4 b4 = ((const float4*)bb)[l];
        shT[(4*l+0)*2 + wid] = (xv4.x - m)*rinv*g4.x + b4.x;
        shT[(4*l+1)*2 + wid] = (xv4.y - m)*rinv*g4.y + b4.y;
        shT[(4*l+2)*2 + wid] = (xv4.z - m)*rinv*g4.z + b4.z;
        shT[(4*l+3)*2 + wid] = (xv4.w - m)*rinv*g4.w + b4.w;
    }
    __syncthreads();
    // W1 + gelu: thread owns channels 4t..4t+3, rows 0..1
    {
        const float4 bc = ((const float4*)b1)[t];
        float A00 = bc.x, A01 = bc.x;
        float A10 = bc.y, A11 = bc.y;
        float A20 = bc.z, A21 = bc.z;
        float A30 = bc.w, A31 = bc.w;
        const float4* W14 = (const float4*)W1;
        for (int d = 0; d < 256; ++d) {
            const float2 s2 = *((const float2*)&shT[d*2]);
            const float4 w4 = W14[d*256 + t];
            A00 = fmaf(s2.x, w4.x, A00); A01 = fmaf(s2.y, w4.x, A01);
            A10 = fmaf(s2.x, w4.y, A10); A11 = fmaf(s2.y, w4.y, A11);
            A20 = fmaf(s2.x, w4.z, A20); A21 = fmaf(s2.y, w4.z, A21);
            A30 = fmaf(s2.x, w4.w, A30); A31 = fmaf(s2.y, w4.w, A31);
        }
        *((float4*)&sfT[0*1024 + 4*t]) = make_float4(gelu_(A00), gelu_(A10), gelu_(A20), gelu_(A30));
        *((float4*)&sfT[1*1024 + 4*t]) = make_float4(gelu_(A01), gelu_(A11), gelu_(A21), gelu_(A31));
    }
    __syncthreads();
    // W2 + residual
    {
        float AO0 = b2[t], AO1 = AO0;
        for (int kk = 0; kk < 1024; ++kk) {
            const float w = W2[kk*256 + t];
            AO0 = fmaf(sfT[kk],        w, AO0);
            AO1 = fmaf(sfT[1024 + kk], w, AO1);
        }
        out[(r0+0)*256 + t] = AO0 + sx1[0][t];
        out[(r0+1)*256 + t] = AO1 + sx1[1][t];
    }
}

extern "C" void kernel_launch(void* const* d_in, const int* in_sizes, int n_in,
                              void* d_out, int out_size, void* d_ws, size_t ws_size,
                              hipStream_t stream) {
    const float* x   = (const float*)d_in[0];
    const float* ef  = (const float*)d_in[1];
    const int*   am  = (const int*)d_in[2];
    const float* ng  = (const float*)d_in[3];
    const float* nb  = (const float*)d_in[4];
    const float* eg  = (const float*)d_in[5];
    const float* ebb = (const float*)d_in[6];
    const float* Wq  = (const float*)d_in[7];
    const float* bq  = (const float*)d_in[8];
    const float* Wk  = (const float*)d_in[9];
    const float* bk  = (const float*)d_in[10];
    const float* Wv  = (const float*)d_in[11];
    const float* bv  = (const float*)d_in[12];
    const float* Wo  = (const float*)d_in[13];
    const float* bo  = (const float*)d_in[14];
    const float* We  = (const float*)d_in[15];
    const float* be  = (const float*)d_in[16];
    const float* fg  = (const float*)d_in[17];
    const float* fb  = (const float*)d_in[18];
    const float* W1  = (const float*)d_in[19];
    const float* b1  = (const float*)d_in[20];
    const float* W2  = (const float*)d_in[21];
    const float* b2  = (const float*)d_in[22];

    float* ws  = (float*)d_ws;
    float* GW  = ws;                      // 2048 f
    float* Av  = ws + 2048;               // 8 f
    float* Cv  = ws + 2064;               // 8 f
    float* q   = ws + 4096;               // 262144 f (B,N,D)
    float* k   = q  + 262144;
    float* v   = k  + 262144;
    float* ao  = v  + 262144;             // 262144 f (B,N,D)

    hipLaunchKernelGGL(k_qkv, dim3(512), dim3(256), 0, stream,
                       x, ng, nb, Wq, bq, Wk, bk, Wv, bv,
                       eg, ebb, We, be, GW, Av, Cv, q, k, v);
    hipLaunchKernelGGL(k_eattn, dim3(1024), dim3(256), 0, stream,
                       (const float4*)ef, am, GW, Av, Cv, q, (const float4*)k, v, ao);
    hipLaunchKernelGGL(k_projff, dim3(512), dim3(256), 0, stream,
                       ao, Wo, bo, x, fg, fb, W1, b1, W2, b2, (float*)d_out);
}